// Round 9
// baseline (27673.428 us; speedup 1.0000x reference)
//
#include <hip/hip_runtime.h>
#include <math.h>

#define DI __device__ __forceinline__

namespace {

typedef unsigned short u16;
typedef unsigned int u32;
typedef __attribute__((ext_vector_type(8))) short bf8;   // 8 bf16
typedef __attribute__((ext_vector_type(4))) float f4;

DI f4 MFB(bf8 a, bf8 b, f4 c) { return __builtin_amdgcn_mfma_f32_16x16x32_bf16(a, b, c, 0, 0, 0); }

constexpr int DOUTS[6] = {1024, 1024, 1024, 1, 1, 1024};
constexpr int BIGM[4] = {0, 1, 2, 5};

constexpr long SZ_BIGM = 2100224, SZ_SMALLM = 1051648;
constexpr long MODOFF[6] = {0, SZ_BIGM, 2 * SZ_BIGM, 3 * SZ_BIGM,
                            3 * SZ_BIGM + SZ_SMALLM, 3 * SZ_BIGM + 2 * SZ_SMALLM};
constexpr long BSTRIDE = 3 * SZ_BIGM + 2 * SZ_SMALLM + SZ_BIGM;

constexpr long OFF_Z      = 0;
constexpr long OFF_STATE  = 8388608;
constexpr long OFF_SPRE5  = 50405376;   // 327680
constexpr long OFF_KVQ    = 50733056;   // 196608
constexpr long OFF_KVQP   = 50929664;   // 294912 fl = 12 bufs x 49152 u16
constexpr long OFF_SPREV  = 51224576;   // 393216 (fp32; only m=3,4 written/consumed)
constexpr long OFF_SPREVP = 51617792;   // 393216 fl = 16 big bufs
constexpr long OFF_PREK   = 52011008;   // 393216
constexpr long OFF_SPREK  = 52404224;   // 393216
constexpr long OFF_SPREKP = 52797440;   // 393216 fl = 16 big bufs
constexpr long OFF_SPREOP = 53190656;   // 98304 fl = 4 bufs (planes only)
constexpr long OFF_ERR    = 53288960;   // 393216
constexpr long OFF_ERRP   = 53682176;   // 393216 fl = 16 big bufs
constexpr long OFF_DLP    = 54075392;   // 393216
constexpr long OFF_RSSQ   = 54468608;   // [2][4][2][16]
constexpr long OFF_EA     = 54468864;   // 8
constexpr long OFF_SUMSQ  = 54468872;   // [2][96]
constexpr long OFF_FLAG   = 54469064;
constexpr long WS_FLOATS  = 54469072;   // 217.9 MB (< 218.6 proven available)

struct InPtrs { const float* p[31]; };

DI float* modBase(float* ws, int b, int m) {
  return ws + OFF_STATE + (long)b * BSTRIDE + MODOFF[m];
}
DI float* vecp(float* base, int m) { return base + ((m == 3 || m == 4) ? 1048576 : 2097152); }
DI u16* planeBuf(float* ws, long offFl, int idx) {
  return (u16*)(ws + offFl) + (long)idx * 49152;
}
DI int sidx(int b, int m, int p) { return ((b * 6 + m) << 2) + p; }
DI float maxnf(int m, int p) {
  switch (p) {
    case 0: return sqrtf((float)(1024 * DOUTS[m]));
    case 1: return sqrtf((float)DOUTS[m]);
    case 2: return 1024.0f;
    default: return 32.0f;
  }
}
DI float sclOf(const float* ws, int sp, int b, int m, int p) {
  const float S = ws[OFF_SUMSQ + sp * 96 + sidx(b, m, p)];
  return fminf(maxnf(m, p) / (sqrtf(S) + 1e-8f), 1.0f);
}
DI float sigm(float x) { return 1.0f / (1.0f + expf(-x)); }
DI float silu(float x) { return x * sigm(x); }
DI u16 f2bf(float x) {
  u32 u = __float_as_uint(x);
  return (u16)((u + 0x7fffu + ((u >> 16) & 1u)) >> 16);
}

DI void sumsqReduce(float ss, float* slack, float* dst) {
#pragma unroll
  for (int st = 32; st >= 1; st >>= 1) ss += __shfl_xor(ss, st);
  const int tid = threadIdx.x;
  if ((tid & 63) == 0) slack[tid >> 6] = ss;
  __syncthreads();
  if (tid == 0) atomicAdd(dst, slack[0] + slack[1] + slack[2] + slack[3]);
  __syncthreads();
}

// 3-plane bf16 split (vector, for on-the-fly W/X)
DI void split3v(const float v[8], bf8& p0, bf8& p1, bf8& p2) {
#pragma unroll
  for (int i = 0; i < 8; i++) {
    const u32 u = __float_as_uint(v[i]);
    const float f0 = __uint_as_float(u & 0xffff0000u);
    const float r1 = v[i] - f0;
    const u32 u1 = __float_as_uint(r1);
    const float f1 = __uint_as_float(u1 & 0xffff0000u);
    const float r2 = r1 - f1;
    p0[i] = (short)(u >> 16);
    p1[i] = (short)(u1 >> 16);
    p2[i] = (short)f2bf(r2);
  }
}
DI void split3p(const float* p, bf8& p0, bf8& p1, bf8& p2) {
  const float4 a = *(const float4*)p, b = *(const float4*)(p + 4);
  const float v[8] = {a.x, a.y, a.z, a.w, b.x, b.y, b.z, b.w};
  split3v(v, p0, p1, p2);
}
// scalar split (emit path) — identical math to split3v
DI void split3s(float x, u16& h, u16& m, u16& l) {
  const u32 u = __float_as_uint(x);
  h = (u16)(u >> 16);
  const float r1 = x - __uint_as_float(u & 0xffff0000u);
  const u32 u1 = __float_as_uint(r1);
  m = (u16)(u1 >> 16);
  const float r2 = r1 - __uint_as_float(u1 & 0xffff0000u);
  l = f2bf(r2);
}
DI void emitPlanes(u16* P, int c, int n, float val) {
  u16 h, m, l;
  split3s(val, h, m, l);
  u16* q = P + (long)c * 1024 + n;
  q[0] = h; q[16384] = m; q[32768] = l;
}

__global__ void k_probe(float* ws) {
  const int l = threadIdx.x, cl = l & 15, kq = l >> 4;
  bf8 af, bf_;
#pragma unroll
  for (int i = 0; i < 8; i++) { af[i] = 0; bf_[i] = 0; }
  if (kq == 0) {
    af[0] = (short)f2bf((float)(cl + 1));
    bf_[0] = (short)f2bf((float)(128 * (cl + 1)));
  }
  f4 d = MFB(af, bf_, f4{0.f, 0.f, 0.f, 0.f});
  bool m0 = true, m1 = true;
#pragma unroll
  for (int r = 0; r < 4; r++) {
    m0 = m0 && (d[r] == (float)((kq * 4 + r + 1) * 128 * (cl + 1)));
    m1 = m1 && (d[r] == (float)((cl + 1) * 128 * (kq * 4 + r + 1)));
  }
  const unsigned long long b0 = __ballot(m0), b1 = __ballot(m1);
  if (l == 0) ws[OFF_FLAG] = (b0 == ~0ull) ? 0.f : ((b1 == ~0ull) ? 1.f : 0.f);
}

// ============ K-split bf16x3 MFMA cores ============
// on-the-fly X split (s1, s2, gbig)
template <class EF>
DI void mcK1(float* sm, const float* __restrict__ X, const float* W,
             int n0, int flg, EF&& ef) {
  const int tid = threadIdx.x, g = tid >> 6, l = tid & 63, cl = l & 15, kq = l >> 4;
  f4 acc = {0.f, 0.f, 0.f, 0.f};
  const float* Xr = X + (long)cl * 1024 + g * 256 + kq * 8;
  const float* Wr = W + (long)(n0 + cl) * 1024 + g * 256 + kq * 8;
#pragma unroll 2
  for (int ch = 0; ch < 8; ch++) {
    bf8 x0, x1, x2, w0, w1, w2;
    split3p(Xr + ch * 32, x0, x1, x2);
    split3p(Wr + ch * 32, w0, w1, w2);
    acc = MFB(x2, w0, acc); acc = MFB(x1, w1, acc); acc = MFB(x0, w2, acc);
    acc = MFB(x1, w0, acc); acc = MFB(x0, w1, acc); acc = MFB(x0, w0, acc);
  }
  *(f4*)(sm + g * 256 + l * 4) = acc;
  __syncthreads();
  const int le = tid >> 2, re = tid & 3;
  const float v = sm[le * 4 + re] + sm[256 + le * 4 + re] +
                  sm[512 + le * 4 + re] + sm[768 + le * 4 + re];
  const int ccl = le & 15, ckq = le >> 4;
  const int c = flg ? ccl : ckq * 4 + re;
  const int n = n0 + (flg ? ckq * 4 + re : ccl);
  ef(c, n, v);
}

// pre-split X planes
template <class EF>
DI void mcK1p(float* sm, const u16* __restrict__ XP, const float* W,
              int n0, int flg, EF&& ef) {
  const int tid = threadIdx.x, g = tid >> 6, l = tid & 63, cl = l & 15, kq = l >> 4;
  f4 acc = {0.f, 0.f, 0.f, 0.f};
  const u16* Xp = XP + (long)cl * 1024 + g * 256 + kq * 8;
  const float* Wr = W + (long)(n0 + cl) * 1024 + g * 256 + kq * 8;
#pragma unroll 2
  for (int ch = 0; ch < 8; ch++) {
    const bf8 x0 = *(const bf8*)(Xp + ch * 32);
    const bf8 x1 = *(const bf8*)(Xp + 16384 + ch * 32);
    const bf8 x2 = *(const bf8*)(Xp + 32768 + ch * 32);
    bf8 w0, w1, w2;
    split3p(Wr + ch * 32, w0, w1, w2);
    acc = MFB(x2, w0, acc); acc = MFB(x1, w1, acc); acc = MFB(x0, w2, acc);
    acc = MFB(x1, w0, acc); acc = MFB(x0, w1, acc); acc = MFB(x0, w0, acc);
  }
  *(f4*)(sm + g * 256 + l * 4) = acc;
  __syncthreads();
  const int le = tid >> 2, re = tid & 3;
  const float v = sm[le * 4 + re] + sm[256 + le * 4 + re] +
                  sm[512 + le * 4 + re] + sm[768 + le * 4 + re];
  const int ccl = le & 15, ckq = le >> 4;
  const int c = flg ? ccl : ckq * 4 + re;
  const int n = n0 + (flg ? ckq * 4 + re : ccl);
  ef(c, n, v);
}

// dual pre-split X planes
template <class EF>
DI void mcK2p(float* sm, const u16* __restrict__ X1P, const u16* __restrict__ X2P,
              const float* W, int n0, int flg, EF&& ef) {
  const int tid = threadIdx.x, g = tid >> 6, l = tid & 63, cl = l & 15, kq = l >> 4;
  f4 a1 = {0.f, 0.f, 0.f, 0.f}, a2 = {0.f, 0.f, 0.f, 0.f};
  const u16* X1p = X1P + (long)cl * 1024 + g * 256 + kq * 8;
  const u16* X2p = X2P + (long)cl * 1024 + g * 256 + kq * 8;
  const float* Wr = W + (long)(n0 + cl) * 1024 + g * 256 + kq * 8;
#pragma unroll 2
  for (int ch = 0; ch < 8; ch++) {
    bf8 w0, w1, w2;
    split3p(Wr + ch * 32, w0, w1, w2);
    const bf8 x0 = *(const bf8*)(X1p + ch * 32);
    const bf8 x1 = *(const bf8*)(X1p + 16384 + ch * 32);
    const bf8 x2 = *(const bf8*)(X1p + 32768 + ch * 32);
    const bf8 y0 = *(const bf8*)(X2p + ch * 32);
    const bf8 y1 = *(const bf8*)(X2p + 16384 + ch * 32);
    const bf8 y2 = *(const bf8*)(X2p + 32768 + ch * 32);
    a1 = MFB(x2, w0, a1); a1 = MFB(x1, w1, a1); a1 = MFB(x0, w2, a1);
    a1 = MFB(x1, w0, a1); a1 = MFB(x0, w1, a1); a1 = MFB(x0, w0, a1);
    a2 = MFB(y2, w0, a2); a2 = MFB(y1, w1, a2); a2 = MFB(y0, w2, a2);
    a2 = MFB(y1, w0, a2); a2 = MFB(y0, w1, a2); a2 = MFB(y0, w0, a2);
  }
  *(f4*)(sm + g * 256 + l * 4) = a1;
  *(f4*)(sm + 1024 + g * 256 + l * 4) = a2;
  __syncthreads();
  const int le = tid >> 2, re = tid & 3;
  const float v1 = sm[le * 4 + re] + sm[256 + le * 4 + re] +
                   sm[512 + le * 4 + re] + sm[768 + le * 4 + re];
  const float v2 = sm[1024 + le * 4 + re] + sm[1280 + le * 4 + re] +
                   sm[1536 + le * 4 + re] + sm[1792 + le * 4 + re];
  const int ccl = le & 15, ckq = le >> 4;
  const int c = flg ? ccl : ckq * 4 + re;
  const int n = n0 + (flg ? ckq * 4 + re : ccl);
  ef(c, n, v1, v2);
}

// transposed-W core, pre-split X planes (s5)
template <class EF>
DI void mcK1tp(float* sm, const u16* __restrict__ EP, const float* W1,
               int h0, int flg, EF&& ef) {
  const int tid = threadIdx.x, g = tid >> 6, l = tid & 63, cl = l & 15, kq = l >> 4;
  f4 acc = {0.f, 0.f, 0.f, 0.f};
  const u16* Ep = EP + (long)cl * 1024 + g * 256 + kq * 8;
  const float* Wc = W1 + (long)(g * 256 + kq * 8) * 1024 + h0 + cl;
#pragma unroll 2
  for (int ch = 0; ch < 8; ch++) {
    const bf8 x0 = *(const bf8*)(Ep + ch * 32);
    const bf8 x1 = *(const bf8*)(Ep + 16384 + ch * 32);
    const bf8 x2 = *(const bf8*)(Ep + 32768 + ch * 32);
    float v[8];
#pragma unroll
    for (int i = 0; i < 8; i++) v[i] = Wc[(long)(ch * 32 + i) * 1024];
    bf8 w0, w1, w2;
    split3v(v, w0, w1, w2);
    acc = MFB(x2, w0, acc); acc = MFB(x1, w1, acc); acc = MFB(x0, w2, acc);
    acc = MFB(x1, w0, acc); acc = MFB(x0, w1, acc); acc = MFB(x0, w0, acc);
  }
  *(f4*)(sm + g * 256 + l * 4) = acc;
  __syncthreads();
  const int le = tid >> 2, re = tid & 3;
  const float v = sm[le * 4 + re] + sm[256 + le * 4 + re] +
                  sm[512 + le * 4 + re] + sm[768 + le * 4 + re];
  const int ccl = le & 15, ckq = le >> 4;
  const int c = flg ? ccl : ckq * 4 + re;
  const int h = h0 + (flg ? ckq * 4 + re : ccl);
  ef(c, h, v);
}

// ============================ prologue ============================

__global__ __launch_bounds__(256) void k_p0(float* ws, InPtrs in) {
  const long i = threadIdx.x + (long)blockIdx.x * 256;
  if (i < 256) { ws[OFF_RSSQ + i] = 0.f; return; }
  if (i < 448) { ws[OFF_SUMSQ + (i - 256)] = 0.f; return; }
  if (i < 456) { ws[OFF_EA + (i - 448)] = 0.f; return; }
  const long j = i - 456;
  if (j < 24 * 2048) {
    const int bm = (int)(j >> 11), q = (int)(j & 2047);
    const int b = bm / 6, m = bm % 6;
    float* vc = vecp(modBase(ws, b, m), m);
    if (q < 1024) { if (q < DOUTS[m]) vc[q] = in.p[2 + 4 * m][q]; }
    else vc[1024 + (q - 1024)] = in.p[4 + 4 * m][q - 1024];
    return;
  }
  const long j2 = j - 49152;
  if (j2 < 8192) {
    const int e = (int)(j2 >> 10), b = e >> 1, m = 3 + (e & 1);
    const int h = (int)(j2 & 1023);
    vecp(modBase(ws, b, m), m)[2048 + h] = in.p[1 + 4 * m][h];
  }
}

__global__ __launch_bounds__(256) void k_pc(float* ws, InPtrs in) {
  const int bid = blockIdx.x, job = bid >> 9, sub = bid & 511;
  const long e0 = (long)sub * 2048 + threadIdx.x * 8;
  int m; bool w1;
  if (job < 6) { m = job; w1 = false; }
  else { m = BIGM[job - 6]; w1 = true; }
  const float* src = in.p[(w1 ? 1 : 3) + 4 * m];
  const float4 a = *(const float4*)(src + e0);
  const float4 b4 = *(const float4*)(src + e0 + 4);
#pragma unroll
  for (int q = 0; q < 4; q++) {
    float* dst = modBase(ws, q, m) + (w1 ? 1048576 : 0);
    *(float4*)(dst + e0) = a;
    *(float4*)(dst + e0 + 4) = b4;
  }
}

__global__ __launch_bounds__(256) void k_gbig(const float* __restrict__ X,
                                              const float* A,
                                              const float* __restrict__ bias,
                                              float* __restrict__ Y,
                                              const float* flagp) {
  __shared__ float sm[1024];
  const int bid = blockIdx.x, nb = bid & 63;
  const long rb = bid >> 6;
  const int flg = (int)flagp[0];
  const float* Xr = X + rb * 16 * 1024;
  float* Yr = Y + rb * 16 * 1024;
  mcK1(sm, Xr, A, nb * 16, flg, [&](int c, int n, float v) {
    Yr[(long)c * 1024 + n] = v + bias[n];
  });
}

// ============================ per-step ============================

// S1: spre5 = silu(cW2*(z @ W2^T) + cb2*b2). grid 1281 (last block = parity zeroing).
__global__ __launch_bounds__(256) void k_s1(float* ws, int t) {
  __shared__ float sm[1024];
  const int bid = blockIdx.x, tid = threadIdx.x;
  if (bid == 1280) {
    const int pc = t & 1;
    if (tid < 128) ws[OFF_RSSQ + pc * 128 + tid] = 0.f;
    else if (tid < 224) ws[OFF_SUMSQ + pc * 96 + (tid - 128)] = 0.f;
    return;
  }
  const int n0 = (bid & 63) * 16, m = (bid >> 6) % 5, b = bid / 320;
  const int flg = (int)ws[OFF_FLAG];
  const int sp = (t + 1) & 1;
  const float* zc = ws + OFF_Z + ((long)b * 2048 + (long)t * 16) * 1024;
  float* base = modBase(ws, b, m);
  const float cW2 = sclOf(ws, sp, b, m, 2), cb2 = sclOf(ws, sp, b, m, 3);
  const float* b2v = vecp(base, m) + 1024;
  float* Y = ws + OFF_SPRE5 + ((long)b * 5 + m) * 16384;
  mcK1(sm, zc, base, n0, flg, [&](int c, int n, float v) {
    Y[(long)c * 1024 + n] = silu(fmaf(cW2, v, cb2 * b2v[n]));
  });
}

// S2: kvq = cW1*(spre5 @ W1^T) + cb1*b1 + z ; emits kvq planes ; rssq ; heads. grid 776.
__global__ __launch_bounds__(256) void k_s2(float* ws, int t) {
  __shared__ float sm[1024 + 16 + 64];
  float* smr = sm + 1024;
  float* sm2 = sm + 1040;
  const int tid = threadIdx.x, bid = blockIdx.x;
  const int sp = (t + 1) & 1, pc = t & 1;
  if (bid < 768) {
    const int n0 = (bid & 63) * 16, m = (bid >> 6) % 3, b = bid / 192;
    const int flg = (int)ws[OFF_FLAG];
    if (tid < 16) smr[tid] = 0.f;
    const float* spre = ws + OFF_SPRE5 + ((long)b * 5 + m) * 16384;
    float* base = modBase(ws, b, m);
    const float* zc = ws + OFF_Z + ((long)b * 2048 + (long)t * 16) * 1024;
    const float cW1 = sclOf(ws, sp, b, m, 0), cb1 = sclOf(ws, sp, b, m, 1);
    const float* b1v = vecp(base, m);
    float* out = ws + OFF_KVQ + ((long)b * 3 + m) * 16384;
    u16* outP = planeBuf(ws, OFF_KVQP, b * 3 + m);
    const bool sq = (m != 1);
    mcK1(sm, spre, base + 1048576, n0, flg, [&](int c, int n, float v) {
      const float val = fmaf(cW1, v, fmaf(cb1, b1v[n], zc[(long)c * 1024 + n]));
      out[(long)c * 1024 + n] = val;
      emitPlanes(outP, c, n, val);
      if (sq) atomicAdd(&smr[c], val * val);
    });
    __syncthreads();
    if (sq && tid < 16)
      atomicAdd(ws + OFF_RSSQ + pc * 128 + (long)b * 32 + (m == 0 ? 0 : 16) + tid,
                smr[tid]);
  } else {
    const int e = bid - 768, b = e >> 1, m = 3 + (e & 1);
    const float* spre = ws + OFF_SPRE5 + ((long)b * 5 + m) * 16384;
    float* base = modBase(ws, b, m);
    const float* w1 = vecp(base, m) + 2048;
    float av[16];
#pragma unroll
    for (int c = 0; c < 16; c++) av[c] = 0.f;
    for (int jj = 0; jj < 4; jj++) {
      const int h = tid + 256 * jj;
      const float w = w1[h];
#pragma unroll
      for (int c = 0; c < 16; c++) av[c] = fmaf(spre[c * 1024 + h], w, av[c]);
    }
#pragma unroll
    for (int st = 1; st < 64; st <<= 1)
#pragma unroll
      for (int c = 0; c < 16; c++) av[c] += __shfl_xor(av[c], st);
    if ((tid & 63) == 0) {
      const int w4 = tid >> 6;
#pragma unroll
      for (int c = 0; c < 16; c++) sm2[w4 * 16 + c] = av[c];
    }
    __syncthreads();
    if (tid == 0) {
      const float cW1 = sclOf(ws, sp, b, m, 0), cb1 = sclOf(ws, sp, b, m, 1);
      const float b10 = vecp(base, m)[0];
      float s = 0.f;
      for (int c = 0; c < 16; c++) {
        const float tot = sm2[c] + sm2[16 + c] + sm2[32 + c] + sm2[48 + c];
        s += sigm(fmaf(cW1, tot, cb1 * b10));
      }
      ws[OFF_EA + ((m == 3) ? 0 : 4) + b] = s * 0.0625f;
    }
  }
}

// S3: dual (v,k)@W2^T from planes -> sprev(P)/prek/sprek(P) ; q@memW2 -> spreoP. grid 1792.
__global__ __launch_bounds__(256) void k_s3(float* ws, int t) {
  __shared__ float sm[2048 + 16];
  float* sminv = sm + 2048;
  const int bid = blockIdx.x, tid = threadIdx.x;
  const int flg = (int)ws[OFF_FLAG];
  const int sp = (t + 1) & 1, pc = t & 1;
  if (bid < 1536) {
    const int n0 = (bid & 63) * 16, m = (bid >> 6) % 6, b = bid / 384;
    if (tid < 16)
      sminv[tid] = 1.f / fmaxf(sqrtf(ws[OFF_RSSQ + pc * 128 + (long)b * 32 + tid]), 1e-12f);
    const u16* vP = planeBuf(ws, OFF_KVQP, b * 3 + 1);
    const u16* kP = planeBuf(ws, OFF_KVQP, b * 3 + 0);
    float* base = modBase(ws, b, m);
    const float cW2 = sclOf(ws, sp, b, m, 2), cb2 = sclOf(ws, sp, b, m, 3);
    const float* b2v = vecp(base, m) + 1024;
    const bool isBig = (m < 3) || (m == 5);
    const int mi = (m == 5) ? 3 : m;
    float* Ysv = ws + OFF_SPREV + ((long)b * 6 + m) * 16384;
    float* Yk = ws + OFF_PREK + ((long)b * 6 + m) * 16384;
    float* Ysk = ws + OFF_SPREK + ((long)b * 6 + m) * 16384;
    u16* PV = isBig ? planeBuf(ws, OFF_SPREVP, b * 4 + mi) : nullptr;
    u16* PK = isBig ? planeBuf(ws, OFF_SPREKP, b * 4 + mi) : nullptr;
    mcK2p(sm, vP, kP, base, n0, flg, [&](int c, int n, float v1, float v2) {
      const float bb = cb2 * b2v[n];
      const float sv = silu(fmaf(cW2, v1, bb));
      const float pk = fmaf(cW2 * sminv[c], v2, bb);
      Yk[(long)c * 1024 + n] = pk;
      const float sk = silu(pk);
      Ysk[(long)c * 1024 + n] = sk;
      if (isBig) {
        emitPlanes(PV, c, n, sv);
        emitPlanes(PK, c, n, sk);
      } else {
        Ysv[(long)c * 1024 + n] = sv;
      }
    });
  } else {
    const int id = bid - 1536, n0 = (id & 63) * 16, b = id >> 6;
    if (tid < 16)
      sminv[tid] = 1.f / fmaxf(sqrtf(ws[OFF_RSSQ + pc * 128 + (long)b * 32 + 16 + tid]), 1e-12f);
    const u16* qP = planeBuf(ws, OFF_KVQP, b * 3 + 2);
    float* base = modBase(ws, b, 5);
    const float cW2 = sclOf(ws, sp, b, 5, 2), cb2 = sclOf(ws, sp, b, 5, 3);
    const float* b2v = vecp(base, 5) + 1024;
    u16* PO = planeBuf(ws, OFF_SPREOP, b);
    mcK1p(sm, qP, base, n0, flg, [&](int c, int n, float v) {
      emitPlanes(PO, c, n, silu(fmaf(cW2 * sminv[c], v, cb2 * b2v[n])));
    });
  }
}

// S4: dual (sprevP,sprekP)@W1^T -> err(+planes) ; spreoP@memW1 -> z ; heads. grid 1288.
__global__ __launch_bounds__(256) void k_s4(float* ws, int t) {
  __shared__ float sm[2048 + 16 + 128];
  float* sminv = sm + 2048;
  float* sm4 = sm + 2064;
  const int tid = threadIdx.x, bid = blockIdx.x;
  const int sp = (t + 1) & 1, pc = t & 1;
  if (bid < 1024) {
    const int n0 = (bid & 63) * 16, mi = (bid >> 6) & 3, b = bid >> 8;
    const int m = BIGM[mi];
    const int flg = (int)ws[OFF_FLAG];
    if (tid < 16)
      sminv[tid] = 1.f / fmaxf(sqrtf(ws[OFF_RSSQ + pc * 128 + (long)b * 32 + tid]), 1e-12f);
    const u16* PV = planeBuf(ws, OFF_SPREVP, b * 4 + mi);
    const u16* PKs = planeBuf(ws, OFF_SPREKP, b * 4 + mi);
    float* base = modBase(ws, b, m);
    const float cW1 = sclOf(ws, sp, b, m, 0), cb1 = sclOf(ws, sp, b, m, 1);
    const float* b1v = vecp(base, m);
    const float* vraw = ws + OFF_KVQ + ((long)b * 3 + 1) * 16384;
    const float* kraw = ws + OFF_KVQ + ((long)b * 3 + 0) * 16384;
    float* errF = ws + OFF_ERR + ((long)b * 6 + m) * 16384;
    u16* errPl = planeBuf(ws, OFF_ERRP, b * 4 + mi);
    mcK2p(sm, PV, PKs, base + 1048576, n0, flg, [&](int c, int n, float v1, float v2) {
      const float bbb = cb1 * b1v[n];
      const float vh = fmaf(cW1, v1, bbb + vraw[(long)c * 1024 + n]);
      const float pr = fmaf(cW1, v2, bbb + kraw[(long)c * 1024 + n] * sminv[c]);
      const float ev = (pr - vh) * 0.0625f;
      errF[(long)c * 1024 + n] = ev;
      emitPlanes(errPl, c, n, ev);
    });
  } else if (bid < 1280) {
    const int id = bid - 1024, n0 = (id & 63) * 16, b = id >> 6;
    const int flg = (int)ws[OFF_FLAG];
    if (tid < 16)
      sminv[tid] = 1.f / fmaxf(sqrtf(ws[OFF_RSSQ + pc * 128 + (long)b * 32 + 16 + tid]), 1e-12f);
    const u16* PO = planeBuf(ws, OFF_SPREOP, b);
    float* base = modBase(ws, b, 5);
    const float cW1 = sclOf(ws, sp, b, 5, 0), cb1 = sclOf(ws, sp, b, 5, 1);
    const float* b1v = vecp(base, 5);
    const float* qraw = ws + OFF_KVQ + ((long)b * 3 + 2) * 16384;
    float* zc = ws + OFF_Z + ((long)b * 2048 + (long)t * 16) * 1024;
    mcK1p(sm, PO, base + 1048576, n0, flg, [&](int c, int n, float v) {
      zc[(long)c * 1024 + n] = fmaf(cW1, v, cb1 * b1v[n] + qraw[(long)c * 1024 + n] * sminv[c]);
    });
  } else {
    const int id = bid - 1280, b = id >> 1, m = 3 + (id & 1);
    const float* sprev = ws + OFF_SPREV + ((long)b * 6 + m) * 16384;
    const float* sprek = ws + OFF_SPREK + ((long)b * 6 + m) * 16384;
    float* base = modBase(ws, b, m);
    const float* w1 = vecp(base, m) + 2048;
    float av[16], ap[16];
#pragma unroll
    for (int c = 0; c < 16; c++) { av[c] = 0.f; ap[c] = 0.f; }
    for (int jj = 0; jj < 4; jj++) {
      const int h = tid + 256 * jj;
      const float w = w1[h];
#pragma unroll
      for (int c = 0; c < 16; c++) {
        av[c] = fmaf(sprev[c * 1024 + h], w, av[c]);
        ap[c] = fmaf(sprek[c * 1024 + h], w, ap[c]);
      }
    }
#pragma unroll
    for (int st = 1; st < 64; st <<= 1)
#pragma unroll
      for (int c = 0; c < 16; c++) {
        av[c] += __shfl_xor(av[c], st);
        ap[c] += __shfl_xor(ap[c], st);
      }
    if ((tid & 63) == 0) {
      const int w4 = tid >> 6;
#pragma unroll
      for (int c = 0; c < 16; c++) { sm4[w4 * 32 + c] = av[c]; sm4[w4 * 32 + 16 + c] = ap[c]; }
    }
    __syncthreads();
    if (tid == 0) {
      const float cW1 = sclOf(ws, sp, b, m, 0), cb1 = sclOf(ws, sp, b, m, 1);
      const float b10 = vecp(base, m)[0];
      float* errF = ws + OFF_ERR + ((long)b * 6 + m) * 16384;
      for (int c = 0; c < 16; c++) {
        const float sv = sm4[c] + sm4[32 + c] + sm4[64 + c] + sm4[96 + c];
        const float sp2 = sm4[16 + c] + sm4[48 + c] + sm4[80 + c] + sm4[112 + c];
        errF[c * 1024] = (fmaf(cW1, sp2, cb1 * b10) - fmaf(cW1, sv, cb1 * b10)) * 0.0625f;
      }
    }
  }
}

// S5: dlp = cW1*(err@W1)*silu_grad(prek), err from planes. grid 1056.
__global__ __launch_bounds__(256) void k_s5(float* ws, int t) {
  __shared__ float sm[1024];
  const int tid = threadIdx.x, bid = blockIdx.x;
  const int sp = (t + 1) & 1;
  if (bid < 1024) {
    const int h0 = (bid & 63) * 16, mi = (bid >> 6) & 3, b = bid >> 8;
    const int m = BIGM[mi];
    const int flg = (int)ws[OFF_FLAG];
    float* base = modBase(ws, b, m);
    const u16* errPl = planeBuf(ws, OFF_ERRP, b * 4 + mi);
    const float cW1 = sclOf(ws, sp, b, m, 0);
    const float* prek = ws + OFF_PREK + ((long)b * 6 + m) * 16384;
    float* dlp = ws + OFF_DLP + ((long)b * 6 + m) * 16384;
    mcK1tp(sm, errPl, base + 1048576, h0, flg, [&](int c, int h, float v) {
      const float pre = prek[(long)c * 1024 + h];
      const float sg = sigm(pre);
      dlp[(long)c * 1024 + h] = cW1 * v * (sg * (1.f + pre * (1.f - sg)));
    });
  } else {
    const int e = bid - 1024, sub = e & 3, bm = e >> 2, b = bm >> 1, m = 3 + (bm & 1);
    const float cW1 = sclOf(ws, sp, b, m, 0);
    const float* errF = ws + OFF_ERR + ((long)b * 6 + m) * 16384;
    const float* prek = ws + OFF_PREK + ((long)b * 6 + m) * 16384;
    const float* w1 = vecp(modBase(ws, b, m), m) + 2048;
    float* dlp = ws + OFF_DLP + ((long)b * 6 + m) * 16384;
    for (int i = tid; i < 4096; i += 256) {
      const long idx = (long)sub * 4096 + i;
      const int c = (int)(idx >> 10), h = (int)(idx & 1023);
      const float pre = prek[idx];
      const float sg = sigm(pre);
      dlp[idx] = errF[c * 1024] * cW1 * w1[h] * (sg * (1.f + pre * (1.f - sg)));
    }
  }
}

// S6: fused grad + decay-update + sumsq. grid 696.
__global__ __launch_bounds__(256) void k_s6(float* ws, int t) {
  __shared__ float sm[64 * 20 + 8];
  float* slack = sm + 64 * 20;
  const int tid = threadIdx.x, bid = blockIdx.x;
  const int sp = (t + 1) & 1, pc = t & 1;
  if (bid < 640) {
    const bool isW2 = bid < 384;
    int b, m, r0, pslot;
    float* W;
    float4 fac[16];
    const float* tsrc;
    if (isW2) {
      const int bm = bid >> 4;
      b = bm / 6; m = bm % 6; r0 = (bid & 15) * 64;
      W = modBase(ws, b, m);
      pslot = 2;
      tsrc = ws + OFF_DLP + ((long)b * 6 + m) * 16384;
      const float* kraw = ws + OFF_KVQ + ((long)b * 3) * 16384;
#pragma unroll
      for (int c = 0; c < 16; c++) {
        const float inv = 1.f / fmaxf(sqrtf(ws[OFF_RSSQ + pc * 128 + (long)b * 32 + c]), 1e-12f);
        const float4 kk = *(const float4*)(kraw + (long)c * 1024 + tid * 4);
        fac[c].x = kk.x * inv; fac[c].y = kk.y * inv;
        fac[c].z = kk.z * inv; fac[c].w = kk.w * inv;
      }
    } else {
      const int id = bid - 384, bm = id >> 4;
      b = bm >> 2; m = BIGM[bm & 3]; r0 = (id & 15) * 64;
      W = modBase(ws, b, m) + 1048576;
      pslot = 0;
      tsrc = ws + OFF_ERR + ((long)b * 6 + m) * 16384;
      const float* sprek = ws + OFF_SPREK + ((long)b * 6 + m) * 16384;
#pragma unroll
      for (int c = 0; c < 16; c++)
        fac[c] = *(const float4*)(sprek + (long)c * 1024 + tid * 4);
    }
    for (int f = tid; f < 1024; f += 256) {
      const int c = f >> 6, hh = f & 63;
      sm[hh * 20 + c] = tsrc[(long)c * 1024 + r0 + hh];
    }
    __syncthreads();
    const float ea = ws[OFF_EA + b], aa = ws[OFF_EA + 4 + b];
    const float ac = aa * sclOf(ws, sp, b, m, pslot);
    float ss = 0.f;
#pragma unroll 1
    for (int hh = 0; hh < 64; hh++) {
      const float4 q0 = *(const float4*)(sm + hh * 20);
      const float4 q1 = *(const float4*)(sm + hh * 20 + 4);
      const float4 q2 = *(const float4*)(sm + hh * 20 + 8);
      const float4 q3 = *(const float4*)(sm + hh * 20 + 12);
      float4 g = {0.f, 0.f, 0.f, 0.f};
#pragma unroll
      for (int c = 0; c < 16; c++) {
        const float4 qq = c < 4 ? q0 : (c < 8 ? q1 : (c < 12 ? q2 : q3));
        const float dv = (&qq.x)[c & 3];
        g.x = fmaf(dv, fac[c].x, g.x);
        g.y = fmaf(dv, fac[c].y, g.y);
        g.z = fmaf(dv, fac[c].z, g.z);
        g.w = fmaf(dv, fac[c].w, g.w);
      }
      float4* Wp = (float4*)(W + (size_t)(r0 + hh) * 1024 + tid * 4);
      float4 w = *Wp;
      w.x = fmaf(ac, w.x, -ea * g.x);
      w.y = fmaf(ac, w.y, -ea * g.y);
      w.z = fmaf(ac, w.z, -ea * g.z);
      w.w = fmaf(ac, w.w, -ea * g.w);
      *Wp = w;
      ss = fmaf(w.x, w.x, fmaf(w.y, w.y, fmaf(w.z, w.z, fmaf(w.w, w.w, ss))));
    }
    sumsqReduce(ss, slack, ws + OFF_SUMSQ + pc * 96 + sidx(b, m, pslot));
  } else if (bid < 688) {
    const int id = bid - 640;
    const int b = id / 12, r = id % 12, m = r >> 1, which = r & 1;
    const float ea = ws[OFF_EA + b], aa = ws[OFF_EA + 4 + b];
    float* vc = vecp(modBase(ws, b, m), m);
    float ss = 0.f;
    if (which == 0) {
      const int n = DOUTS[m];
      const float* errF = ws + OFF_ERR + ((long)b * 6 + m) * 16384;
      const float ac = aa * sclOf(ws, sp, b, m, 1);
      for (int o = tid; o < n; o += 256) {
        float gs = 0.f;
#pragma unroll
        for (int c = 0; c < 16; c++) gs += errF[c * 1024 + o];
        const float nw = fmaf(ac, vc[o], -ea * gs);
        vc[o] = nw;
        ss = fmaf(nw, nw, ss);
      }
      sumsqReduce(ss, slack, ws + OFF_SUMSQ + pc * 96 + sidx(b, m, 1));
    } else {
      const float* dlpP = ws + OFF_DLP + ((long)b * 6 + m) * 16384;
      const float ac = aa * sclOf(ws, sp, b, m, 3);
      for (int h = tid; h < 1024; h += 256) {
        float gs = 0.f;
#pragma unroll
        for (int c = 0; c < 16; c++) gs += dlpP[c * 1024 + h];
        const float nw = fmaf(ac, vc[1024 + h], -ea * gs);
        vc[1024 + h] = nw;
        ss = fmaf(nw, nw, ss);
      }
      sumsqReduce(ss, slack, ws + OFF_SUMSQ + pc * 96 + sidx(b, m, 3));
    }
  } else {
    const int e2 = bid - 688, b = e2 >> 1, m = 3 + (e2 & 1);
    const float ea = ws[OFF_EA + b], aa = ws[OFF_EA + 4 + b];
    float* vc = vecp(modBase(ws, b, m), m);
    const float* errF = ws + OFF_ERR + ((long)b * 6 + m) * 16384;
    const float* sprek = ws + OFF_SPREK + ((long)b * 6 + m) * 16384;
    const float ac = aa * sclOf(ws, sp, b, m, 0);
    float ss = 0.f;
    for (int h = tid; h < 1024; h += 256) {
      float gs = 0.f;
#pragma unroll
      for (int c = 0; c < 16; c++)
        gs = fmaf(errF[c * 1024], sprek[c * 1024 + h], gs);
      const float nw = fmaf(ac, vc[2048 + h], -ea * gs);
      vc[2048 + h] = nw;
      ss = fmaf(nw, nw, ss);
    }
    sumsqReduce(ss, slack, ws + OFF_SUMSQ + pc * 96 + sidx(b, m, 0));
  }
}

// ============================ epilogue ============================

__global__ __launch_bounds__(256) void k_ln(float* ws, const float* __restrict__ g,
                                            const float* __restrict__ bb) {
  __shared__ float sm[8];
  float* p = ws + OFF_Z + (long)blockIdx.x * 1024;
  const int tid = threadIdx.x;
  float s = 0.f, s2 = 0.f;
  for (int j = tid; j < 1024; j += 256) {
    const float v = p[j];
    s += v;
    s2 = fmaf(v, v, s2);
  }
#pragma unroll
  for (int st = 32; st >= 1; st >>= 1) { s += __shfl_xor(s, st); s2 += __shfl_xor(s2, st); }
  if ((tid & 63) == 0) { sm[tid >> 6] = s; sm[4 + (tid >> 6)] = s2; }
  __syncthreads();
  const float S = sm[0] + sm[1] + sm[2] + sm[3];
  const float S2 = sm[4] + sm[5] + sm[6] + sm[7];
  const float mu = S * (1.f / 1024.f);
  const float var = S2 * (1.f / 1024.f) - mu * mu;
  const float inv = 1.f / sqrtf(var + 1e-5f);
  for (int j = tid; j < 1024; j += 256) {
    p[j] = fmaf((p[j] - mu) * inv, g[j], bb[j]);
  }
}

}  // namespace

extern "C" void kernel_launch(void* const* d_in, const int* in_sizes, int n_in,
                              void* d_out, int out_size, void* d_ws, size_t ws_size,
                              hipStream_t stream) {
  (void)in_sizes; (void)n_in; (void)out_size;
  if (ws_size < (size_t)WS_FLOATS * sizeof(float)) return;
  float* ws = (float*)d_ws;
  InPtrs ip;
  for (int i = 0; i < 31; i++) ip.p[i] = (const float*)d_in[i];

  k_probe<<<1, 64, 0, stream>>>(ws);
  k_p0<<<256, 256, 0, stream>>>(ws, ip);
  k_pc<<<5120, 256, 0, stream>>>(ws, ip);
  k_gbig<<<32768, 256, 0, stream>>>((const float*)d_in[0], (const float*)d_in[25],
                                    (const float*)d_in[26], ws + OFF_Z, ws + OFF_FLAG);

  for (int t = 0; t < 128; t++) {
    k_s1<<<1281, 256, 0, stream>>>(ws, t);
    k_s2<<<776, 256, 0, stream>>>(ws, t);
    k_s3<<<1792, 256, 0, stream>>>(ws, t);
    k_s4<<<1288, 256, 0, stream>>>(ws, t);
    k_s5<<<1056, 256, 0, stream>>>(ws, t);
    k_s6<<<696, 256, 0, stream>>>(ws, t);
  }

  k_ln<<<8192, 256, 0, stream>>>(ws, (const float*)d_in[29], (const float*)d_in[30]);
  k_gbig<<<32768, 256, 0, stream>>>(ws + OFF_Z, (const float*)d_in[27],
                                    (const float*)d_in[28], (float*)d_out, ws + OFF_FLAG);
}

// Round 10
// 21892.613 us; speedup vs baseline: 1.2641x; 1.2641x over previous
//
#include <hip/hip_runtime.h>
#include <math.h>

#define DI __device__ __forceinline__

namespace {

typedef unsigned short u16;
typedef unsigned int u32;
typedef __attribute__((ext_vector_type(8))) short bf8;   // 8 bf16
typedef __attribute__((ext_vector_type(4))) float f4;

DI f4 MFB(bf8 a, bf8 b, f4 c) { return __builtin_amdgcn_mfma_f32_16x16x32_bf16(a, b, c, 0, 0, 0); }

constexpr int DOUTS[6] = {1024, 1024, 1024, 1, 1, 1024};
constexpr int BIGM[4] = {0, 1, 2, 5};

constexpr long SZ_BIGM = 2100224, SZ_SMALLM = 1051648;
constexpr long MODOFF[6] = {0, SZ_BIGM, 2 * SZ_BIGM, 3 * SZ_BIGM,
                            3 * SZ_BIGM + SZ_SMALLM, 3 * SZ_BIGM + 2 * SZ_SMALLM};
constexpr long BSTRIDE = 3 * SZ_BIGM + 2 * SZ_SMALLM + SZ_BIGM;

constexpr long OFF_Z     = 0;
constexpr long OFF_STATE = 8388608;
constexpr long OFF_SPRE5 = OFF_STATE + 4 * BSTRIDE;
constexpr long OFF_KVQ   = OFF_SPRE5 + 327680;
constexpr long OFF_SPREV = OFF_KVQ + 196608;
constexpr long OFF_PREK  = OFF_SPREV + 393216;
constexpr long OFF_SPREK = OFF_PREK + 393216;
constexpr long OFF_SPREO = OFF_SPREK + 393216;
constexpr long OFF_ERR   = OFF_SPREO + 65536;
constexpr long OFF_DLP   = OFF_ERR + 393216;
constexpr long OFF_RSSQ  = OFF_DLP + 393216;   // [2][4][2][16] = 256 (parity)
constexpr long OFF_EA    = OFF_RSSQ + 256;     // 8
constexpr long OFF_SUMSQ = OFF_EA + 8;         // [2][96] = 192 (parity)
constexpr long OFF_FLAG  = OFF_SUMSQ + 192;
constexpr long WS_FLOATS = OFF_FLAG + 8;       // ~52.96M floats = 211.9 MB

struct InPtrs { const float* p[31]; };

DI float* modBase(float* ws, int b, int m) {
  return ws + OFF_STATE + (long)b * BSTRIDE + MODOFF[m];
}
DI float* vecp(float* base, int m) { return base + ((m == 3 || m == 4) ? 1048576 : 2097152); }
DI int sidx(int b, int m, int p) { return ((b * 6 + m) << 2) + p; }
DI float maxnf(int m, int p) {
  switch (p) {
    case 0: return sqrtf((float)(1024 * DOUTS[m]));
    case 1: return sqrtf((float)DOUTS[m]);
    case 2: return 1024.0f;
    default: return 32.0f;
  }
}
DI float sclOf(const float* ws, int sp, int b, int m, int p) {
  const float S = ws[OFF_SUMSQ + sp * 96 + sidx(b, m, p)];
  return fminf(maxnf(m, p) / (sqrtf(S) + 1e-8f), 1.0f);
}
DI float sigm(float x) { return 1.0f / (1.0f + expf(-x)); }
DI float silu(float x) { return x * sigm(x); }
DI u16 f2bf(float x) {
  u32 u = __float_as_uint(x);
  return (u16)((u + 0x7fffu + ((u >> 16) & 1u)) >> 16);
}

DI void sumsqReduce(float ss, float* slack, float* dst) {
#pragma unroll
  for (int st = 32; st >= 1; st >>= 1) ss += __shfl_xor(ss, st);
  const int tid = threadIdx.x;
  if ((tid & 63) == 0) slack[tid >> 6] = ss;
  __syncthreads();
  if (tid == 0) atomicAdd(dst, slack[0] + slack[1] + slack[2] + slack[3]);
  __syncthreads();
}

// 3-plane bf16 split
DI void split3v(const float v[8], bf8& p0, bf8& p1, bf8& p2) {
#pragma unroll
  for (int i = 0; i < 8; i++) {
    const u32 u = __float_as_uint(v[i]);
    const float f0 = __uint_as_float(u & 0xffff0000u);
    const float r1 = v[i] - f0;
    const u32 u1 = __float_as_uint(r1);
    const float f1 = __uint_as_float(u1 & 0xffff0000u);
    const float r2 = r1 - f1;
    p0[i] = (short)(u >> 16);
    p1[i] = (short)(u1 >> 16);
    p2[i] = (short)f2bf(r2);
  }
}
DI void split3p(const float* p, bf8& p0, bf8& p1, bf8& p2) {
  const float4 a = *(const float4*)p, b = *(const float4*)(p + 4);
  const float v[8] = {a.x, a.y, a.z, a.w, b.x, b.y, b.z, b.w};
  split3v(v, p0, p1, p2);
}

__global__ void k_probe(float* ws) {
  const int l = threadIdx.x, cl = l & 15, kq = l >> 4;
  bf8 af, bf_;
#pragma unroll
  for (int i = 0; i < 8; i++) { af[i] = 0; bf_[i] = 0; }
  if (kq == 0) {
    af[0] = (short)f2bf((float)(cl + 1));
    bf_[0] = (short)f2bf((float)(128 * (cl + 1)));
  }
  f4 d = MFB(af, bf_, f4{0.f, 0.f, 0.f, 0.f});
  bool m0 = true, m1 = true;
#pragma unroll
  for (int r = 0; r < 4; r++) {
    m0 = m0 && (d[r] == (float)((kq * 4 + r + 1) * 128 * (cl + 1)));
    m1 = m1 && (d[r] == (float)((cl + 1) * 128 * (kq * 4 + r + 1)));
  }
  const unsigned long long b0 = __ballot(m0), b1 = __ballot(m1);
  if (l == 0) ws[OFF_FLAG] = (b0 == ~0ull) ? 0.f : ((b1 == ~0ull) ? 1.f : 0.f);
}

// ============ K-split bf16x3 MFMA cores — 16x32 output tiles ============
// Y[c<16][n0..n0+32) = sum_k X[c][k]*W[n][k]. 256 thr / 4 waves K-split;
// each wave computes BOTH 16-col subtiles (X split shared). LDS combine.
template <class EF>
DI void mcK1(float* sm, const float* __restrict__ X, const float* W,
             int n0, int flg, EF&& ef) {
  const int tid = threadIdx.x, g = tid >> 6, l = tid & 63, cl = l & 15, kq = l >> 4;
  f4 a0 = {0.f, 0.f, 0.f, 0.f}, a1 = {0.f, 0.f, 0.f, 0.f};
  const float* Xr = X + (long)cl * 1024 + g * 256 + kq * 8;
  const float* Wr0 = W + (long)(n0 + cl) * 1024 + g * 256 + kq * 8;
  const float* Wr1 = Wr0 + 16 * 1024;
#pragma unroll 2
  for (int ch = 0; ch < 8; ch++) {
    bf8 x0, x1, x2, w0, w1, w2;
    split3p(Xr + ch * 32, x0, x1, x2);
    split3p(Wr0 + ch * 32, w0, w1, w2);
    a0 = MFB(x2, w0, a0); a0 = MFB(x1, w1, a0); a0 = MFB(x0, w2, a0);
    a0 = MFB(x1, w0, a0); a0 = MFB(x0, w1, a0); a0 = MFB(x0, w0, a0);
    split3p(Wr1 + ch * 32, w0, w1, w2);
    a1 = MFB(x2, w0, a1); a1 = MFB(x1, w1, a1); a1 = MFB(x0, w2, a1);
    a1 = MFB(x1, w0, a1); a1 = MFB(x0, w1, a1); a1 = MFB(x0, w0, a1);
  }
  *(f4*)(sm + g * 256 + l * 4) = a0;
  *(f4*)(sm + 1024 + g * 256 + l * 4) = a1;
  __syncthreads();
  const int le = tid >> 2, re = tid & 3;
  const int ccl = le & 15, ckq = le >> 4;
  const int c = flg ? ccl : ckq * 4 + re;
  const int nb = flg ? ckq * 4 + re : ccl;
#pragma unroll
  for (int half = 0; half < 2; half++) {
    const float v = sm[half * 1024 + le * 4 + re] + sm[half * 1024 + 256 + le * 4 + re] +
                    sm[half * 1024 + 512 + le * 4 + re] + sm[half * 1024 + 768 + le * 4 + re];
    ef(c, n0 + half * 16 + nb, v);
  }
}

// dual-X 16x32: two X streams, two n-subtiles, one W pass per subtile.
template <class EF>
DI void mcK2(float* sm, const float* __restrict__ X1, const float* __restrict__ X2,
             const float* W, int n0, int flg, EF&& ef) {
  const int tid = threadIdx.x, g = tid >> 6, l = tid & 63, cl = l & 15, kq = l >> 4;
  f4 a10 = {0.f, 0.f, 0.f, 0.f}, a11 = {0.f, 0.f, 0.f, 0.f};
  f4 a20 = {0.f, 0.f, 0.f, 0.f}, a21 = {0.f, 0.f, 0.f, 0.f};
  const float* X1r = X1 + (long)cl * 1024 + g * 256 + kq * 8;
  const float* X2r = X2 + (long)cl * 1024 + g * 256 + kq * 8;
  const float* Wr0 = W + (long)(n0 + cl) * 1024 + g * 256 + kq * 8;
  const float* Wr1 = Wr0 + 16 * 1024;
#pragma unroll 2
  for (int ch = 0; ch < 8; ch++) {
    bf8 x0, x1, x2, y0, y1, y2, w0, w1, w2;
    split3p(X1r + ch * 32, x0, x1, x2);
    split3p(X2r + ch * 32, y0, y1, y2);
    split3p(Wr0 + ch * 32, w0, w1, w2);
    a10 = MFB(x2, w0, a10); a10 = MFB(x1, w1, a10); a10 = MFB(x0, w2, a10);
    a10 = MFB(x1, w0, a10); a10 = MFB(x0, w1, a10); a10 = MFB(x0, w0, a10);
    a20 = MFB(y2, w0, a20); a20 = MFB(y1, w1, a20); a20 = MFB(y0, w2, a20);
    a20 = MFB(y1, w0, a20); a20 = MFB(y0, w1, a20); a20 = MFB(y0, w0, a20);
    split3p(Wr1 + ch * 32, w0, w1, w2);
    a11 = MFB(x2, w0, a11); a11 = MFB(x1, w1, a11); a11 = MFB(x0, w2, a11);
    a11 = MFB(x1, w0, a11); a11 = MFB(x0, w1, a11); a11 = MFB(x0, w0, a11);
    a21 = MFB(y2, w0, a21); a21 = MFB(y1, w1, a21); a21 = MFB(y0, w2, a21);
    a21 = MFB(y1, w0, a21); a21 = MFB(y0, w1, a21); a21 = MFB(y0, w0, a21);
  }
  *(f4*)(sm + g * 256 + l * 4) = a10;
  *(f4*)(sm + 1024 + g * 256 + l * 4) = a11;
  *(f4*)(sm + 2048 + g * 256 + l * 4) = a20;
  *(f4*)(sm + 3072 + g * 256 + l * 4) = a21;
  __syncthreads();
  const int le = tid >> 2, re = tid & 3;
  const int ccl = le & 15, ckq = le >> 4;
  const int c = flg ? ccl : ckq * 4 + re;
  const int nb = flg ? ckq * 4 + re : ccl;
#pragma unroll
  for (int half = 0; half < 2; half++) {
    const int o1 = half * 1024 + le * 4 + re, o2 = 2048 + half * 1024 + le * 4 + re;
    const float v1 = sm[o1] + sm[o1 + 256] + sm[o1 + 512] + sm[o1 + 768];
    const float v2 = sm[o2] + sm[o2 + 256] + sm[o2 + 512] + sm[o2 + 768];
    ef(c, n0 + half * 16 + nb, v1, v2);
  }
}

// transposed-W core 16x32 (s5): G[c][h] = sum_o E[c][o]*W1[o][h].
template <class EF>
DI void mcK1t(float* sm, const float* __restrict__ E, const float* W1,
              int h0, int flg, EF&& ef) {
  const int tid = threadIdx.x, g = tid >> 6, l = tid & 63, cl = l & 15, kq = l >> 4;
  f4 a0 = {0.f, 0.f, 0.f, 0.f}, a1 = {0.f, 0.f, 0.f, 0.f};
  const float* Er = E + (long)cl * 1024 + g * 256 + kq * 8;
  const float* Wc0 = W1 + (long)(g * 256 + kq * 8) * 1024 + h0 + cl;
  const float* Wc1 = Wc0 + 16;
#pragma unroll 2
  for (int ch = 0; ch < 8; ch++) {
    bf8 x0, x1, x2, w0, w1, w2;
    split3p(Er + ch * 32, x0, x1, x2);
    float v[8];
#pragma unroll
    for (int i = 0; i < 8; i++) v[i] = Wc0[(long)(ch * 32 + i) * 1024];
    split3v(v, w0, w1, w2);
    a0 = MFB(x2, w0, a0); a0 = MFB(x1, w1, a0); a0 = MFB(x0, w2, a0);
    a0 = MFB(x1, w0, a0); a0 = MFB(x0, w1, a0); a0 = MFB(x0, w0, a0);
#pragma unroll
    for (int i = 0; i < 8; i++) v[i] = Wc1[(long)(ch * 32 + i) * 1024];
    split3v(v, w0, w1, w2);
    a1 = MFB(x2, w0, a1); a1 = MFB(x1, w1, a1); a1 = MFB(x0, w2, a1);
    a1 = MFB(x1, w0, a1); a1 = MFB(x0, w1, a1); a1 = MFB(x0, w0, a1);
  }
  *(f4*)(sm + g * 256 + l * 4) = a0;
  *(f4*)(sm + 1024 + g * 256 + l * 4) = a1;
  __syncthreads();
  const int le = tid >> 2, re = tid & 3;
  const int ccl = le & 15, ckq = le >> 4;
  const int c = flg ? ccl : ckq * 4 + re;
  const int hb = flg ? ckq * 4 + re : ccl;
#pragma unroll
  for (int half = 0; half < 2; half++) {
    const float v = sm[half * 1024 + le * 4 + re] + sm[half * 1024 + 256 + le * 4 + re] +
                    sm[half * 1024 + 512 + le * 4 + re] + sm[half * 1024 + 768 + le * 4 + re];
    ef(c, h0 + half * 16 + hb, v);
  }
}

// ============================ prologue ============================

__global__ __launch_bounds__(256) void k_p0(float* ws, InPtrs in) {
  const long i = threadIdx.x + (long)blockIdx.x * 256;
  if (i < 256) { ws[OFF_RSSQ + i] = 0.f; return; }
  if (i < 448) { ws[OFF_SUMSQ + (i - 256)] = 0.f; return; }
  if (i < 456) { ws[OFF_EA + (i - 448)] = 0.f; return; }
  const long j = i - 456;
  if (j < 24 * 2048) {
    const int bm = (int)(j >> 11), q = (int)(j & 2047);
    const int b = bm / 6, m = bm % 6;
    float* vc = vecp(modBase(ws, b, m), m);
    if (q < 1024) { if (q < DOUTS[m]) vc[q] = in.p[2 + 4 * m][q]; }
    else vc[1024 + (q - 1024)] = in.p[4 + 4 * m][q - 1024];
    return;
  }
  const long j2 = j - 49152;
  if (j2 < 8192) {
    const int e = (int)(j2 >> 10), b = e >> 1, m = 3 + (e & 1);
    const int h = (int)(j2 & 1023);
    vecp(modBase(ws, b, m), m)[2048 + h] = in.p[1 + 4 * m][h];
  }
}

__global__ __launch_bounds__(256) void k_pc(float* ws, InPtrs in) {
  const int bid = blockIdx.x, job = bid >> 9, sub = bid & 511;
  const long e0 = (long)sub * 2048 + threadIdx.x * 8;
  int m; bool w1;
  if (job < 6) { m = job; w1 = false; }
  else { m = BIGM[job - 6]; w1 = true; }
  const float* src = in.p[(w1 ? 1 : 3) + 4 * m];
  const float4 a = *(const float4*)(src + e0);
  const float4 b4 = *(const float4*)(src + e0 + 4);
#pragma unroll
  for (int q = 0; q < 4; q++) {
    float* dst = modBase(ws, q, m) + (w1 ? 1048576 : 0);
    *(float4*)(dst + e0) = a;
    *(float4*)(dst + e0 + 4) = b4;
  }
}

__global__ __launch_bounds__(256) void k_gbig(const float* __restrict__ X,
                                              const float* A,
                                              const float* __restrict__ bias,
                                              float* __restrict__ Y,
                                              const float* flagp) {
  __shared__ float sm[2048];
  const int bid = blockIdx.x, nb = bid & 31;
  const long rb = bid >> 5;
  const int flg = (int)flagp[0];
  const float* Xr = X + rb * 16 * 1024;
  float* Yr = Y + rb * 16 * 1024;
  mcK1(sm, Xr, A, nb * 32, flg, [&](int c, int n, float v) {
    Yr[(long)c * 1024 + n] = v + bias[n];
  });
}

// ============================ per-step ============================

// S1: spre5 = silu(cW2*(z @ W2^T) + cb2*b2). grid 641 (last block = parity zeroing).
__global__ __launch_bounds__(256) void k_s1(float* ws, int t) {
  __shared__ float sm[2048];
  const int bid = blockIdx.x, tid = threadIdx.x;
  if (bid == 640) {
    const int pc = t & 1;
    if (tid < 128) ws[OFF_RSSQ + pc * 128 + tid] = 0.f;
    else if (tid < 224) ws[OFF_SUMSQ + pc * 96 + (tid - 128)] = 0.f;
    return;
  }
  const int n0 = (bid & 31) * 32, m = (bid >> 5) % 5, b = bid / 160;
  const int flg = (int)ws[OFF_FLAG];
  const int sp = (t + 1) & 1;
  const float* zc = ws + OFF_Z + ((long)b * 2048 + (long)t * 16) * 1024;
  float* base = modBase(ws, b, m);
  const float cW2 = sclOf(ws, sp, b, m, 2), cb2 = sclOf(ws, sp, b, m, 3);
  const float* b2v = vecp(base, m) + 1024;
  float* Y = ws + OFF_SPRE5 + ((long)b * 5 + m) * 16384;
  mcK1(sm, zc, base, n0, flg, [&](int c, int n, float v) {
    Y[(long)c * 1024 + n] = silu(fmaf(cW2, v, cb2 * b2v[n]));
  });
}

// S2: kvq = cW1*(spre5 @ W1^T) + cb1*b1 + z ; rssq k,q ; eta/alpha heads. grid 392.
__global__ __launch_bounds__(256) void k_s2(float* ws, int t) {
  __shared__ float sm[2048 + 16 + 64];
  float* smr = sm + 2048;
  float* sm2 = sm + 2064;
  const int tid = threadIdx.x, bid = blockIdx.x;
  const int sp = (t + 1) & 1, pc = t & 1;
  if (bid < 384) {
    const int n0 = (bid & 31) * 32, m = (bid >> 5) % 3, b = bid / 96;
    const int flg = (int)ws[OFF_FLAG];
    if (tid < 16) smr[tid] = 0.f;
    const float* spre = ws + OFF_SPRE5 + ((long)b * 5 + m) * 16384;
    float* base = modBase(ws, b, m);
    const float* zc = ws + OFF_Z + ((long)b * 2048 + (long)t * 16) * 1024;
    const float cW1 = sclOf(ws, sp, b, m, 0), cb1 = sclOf(ws, sp, b, m, 1);
    const float* b1v = vecp(base, m);
    float* out = ws + OFF_KVQ + ((long)b * 3 + m) * 16384;
    const bool sq = (m != 1);
    mcK1(sm, spre, base + 1048576, n0, flg, [&](int c, int n, float v) {
      const float val = fmaf(cW1, v, fmaf(cb1, b1v[n], zc[(long)c * 1024 + n]));
      out[(long)c * 1024 + n] = val;
      if (sq) atomicAdd(&smr[c], val * val);
    });
    __syncthreads();
    if (sq && tid < 16)
      atomicAdd(ws + OFF_RSSQ + pc * 128 + (long)b * 32 + (m == 0 ? 0 : 16) + tid,
                smr[tid]);
  } else {
    const int e = bid - 384, b = e >> 1, m = 3 + (e & 1);
    const float* spre = ws + OFF_SPRE5 + ((long)b * 5 + m) * 16384;
    float* base = modBase(ws, b, m);
    const float* w1 = vecp(base, m) + 2048;
    float av[16];
#pragma unroll
    for (int c = 0; c < 16; c++) av[c] = 0.f;
    for (int jj = 0; jj < 4; jj++) {
      const int h = tid + 256 * jj;
      const float w = w1[h];
#pragma unroll
      for (int c = 0; c < 16; c++) av[c] = fmaf(spre[c * 1024 + h], w, av[c]);
    }
#pragma unroll
    for (int st = 1; st < 64; st <<= 1)
#pragma unroll
      for (int c = 0; c < 16; c++) av[c] += __shfl_xor(av[c], st);
    if ((tid & 63) == 0) {
      const int w4 = tid >> 6;
#pragma unroll
      for (int c = 0; c < 16; c++) sm2[w4 * 16 + c] = av[c];
    }
    __syncthreads();
    if (tid == 0) {
      const float cW1 = sclOf(ws, sp, b, m, 0), cb1 = sclOf(ws, sp, b, m, 1);
      const float b10 = vecp(base, m)[0];
      float s = 0.f;
      for (int c = 0; c < 16; c++) {
        const float tot = sm2[c] + sm2[16 + c] + sm2[32 + c] + sm2[48 + c];
        s += sigm(fmaf(cW1, tot, cb1 * b10));
      }
      ws[OFF_EA + ((m == 3) ? 0 : 4) + b] = s * 0.0625f;
    }
  }
}

// S3: dual (v,k)@W2^T -> sprev/prek/sprek ; q@memW2 -> spreo. grid 896.
__global__ __launch_bounds__(256) void k_s3(float* ws, int t) {
  __shared__ float sm[4096 + 16];
  float* sminv = sm + 4096;
  const int bid = blockIdx.x, tid = threadIdx.x;
  const int flg = (int)ws[OFF_FLAG];
  const int sp = (t + 1) & 1, pc = t & 1;
  if (bid < 768) {
    const int n0 = (bid & 31) * 32, m = (bid >> 5) % 6, b = bid / 192;
    if (tid < 16)
      sminv[tid] = 1.f / fmaxf(sqrtf(ws[OFF_RSSQ + pc * 128 + (long)b * 32 + tid]), 1e-12f);
    const float* vX = ws + OFF_KVQ + ((long)b * 3 + 1) * 16384;
    const float* kX = ws + OFF_KVQ + ((long)b * 3 + 0) * 16384;
    float* base = modBase(ws, b, m);
    const float cW2 = sclOf(ws, sp, b, m, 2), cb2 = sclOf(ws, sp, b, m, 3);
    const float* b2v = vecp(base, m) + 1024;
    float* Ysv = ws + OFF_SPREV + ((long)b * 6 + m) * 16384;
    float* Yk = ws + OFF_PREK + ((long)b * 6 + m) * 16384;
    float* Ysk = ws + OFF_SPREK + ((long)b * 6 + m) * 16384;
    mcK2(sm, vX, kX, base, n0, flg, [&](int c, int n, float v1, float v2) {
      const float bb = cb2 * b2v[n];
      Ysv[(long)c * 1024 + n] = silu(fmaf(cW2, v1, bb));
      const float pk = fmaf(cW2 * sminv[c], v2, bb);
      Yk[(long)c * 1024 + n] = pk;
      Ysk[(long)c * 1024 + n] = silu(pk);
    });
  } else {
    const int id = bid - 768, n0 = (id & 31) * 32, b = id >> 5;
    if (tid < 16)
      sminv[tid] = 1.f / fmaxf(sqrtf(ws[OFF_RSSQ + pc * 128 + (long)b * 32 + 16 + tid]), 1e-12f);
    const float* qX = ws + OFF_KVQ + ((long)b * 3 + 2) * 16384;
    float* base = modBase(ws, b, 5);
    const float cW2 = sclOf(ws, sp, b, 5, 2), cb2 = sclOf(ws, sp, b, 5, 3);
    const float* b2v = vecp(base, 5) + 1024;
    float* Y = ws + OFF_SPREO + (long)b * 16384;
    mcK1(sm, qX, base, n0, flg, [&](int c, int n, float v) {
      Y[(long)c * 1024 + n] = silu(fmaf(cW2 * sminv[c], v, cb2 * b2v[n]));
    });
  }
}

// S4: dual (sprev,sprek)@W1^T -> err ; spreo@memW1 -> z ; eta/alpha heads. grid 648.
__global__ __launch_bounds__(256) void k_s4(float* ws, int t) {
  __shared__ float sm[4096 + 16 + 128];
  float* sminv = sm + 4096;
  float* sm4 = sm + 4112;
  const int tid = threadIdx.x, bid = blockIdx.x;
  const int sp = (t + 1) & 1, pc = t & 1;
  if (bid < 512) {
    const int n0 = (bid & 31) * 32, mi = (bid >> 5) & 3, b = bid >> 7;
    const int m = BIGM[mi];
    const int flg = (int)ws[OFF_FLAG];
    if (tid < 16)
      sminv[tid] = 1.f / fmaxf(sqrtf(ws[OFF_RSSQ + pc * 128 + (long)b * 32 + tid]), 1e-12f);
    const float* sprev = ws + OFF_SPREV + ((long)b * 6 + m) * 16384;
    const float* sprek = ws + OFF_SPREK + ((long)b * 6 + m) * 16384;
    float* base = modBase(ws, b, m);
    const float cW1 = sclOf(ws, sp, b, m, 0), cb1 = sclOf(ws, sp, b, m, 1);
    const float* b1v = vecp(base, m);
    const float* vraw = ws + OFF_KVQ + ((long)b * 3 + 1) * 16384;
    const float* kraw = ws + OFF_KVQ + ((long)b * 3 + 0) * 16384;
    float* errP = ws + OFF_ERR + ((long)b * 6 + m) * 16384;
    mcK2(sm, sprev, sprek, base + 1048576, n0, flg, [&](int c, int n, float v1, float v2) {
      const float bbb = cb1 * b1v[n];
      const float vh = fmaf(cW1, v1, bbb + vraw[(long)c * 1024 + n]);
      const float pr = fmaf(cW1, v2, bbb + kraw[(long)c * 1024 + n] * sminv[c]);
      errP[(long)c * 1024 + n] = (pr - vh) * 0.0625f;
    });
  } else if (bid < 640) {
    const int id = bid - 512, n0 = (id & 31) * 32, b = id >> 5;
    const int flg = (int)ws[OFF_FLAG];
    if (tid < 16)
      sminv[tid] = 1.f / fmaxf(sqrtf(ws[OFF_RSSQ + pc * 128 + (long)b * 32 + 16 + tid]), 1e-12f);
    const float* spreo = ws + OFF_SPREO + (long)b * 16384;
    float* base = modBase(ws, b, 5);
    const float cW1 = sclOf(ws, sp, b, 5, 0), cb1 = sclOf(ws, sp, b, 5, 1);
    const float* b1v = vecp(base, 5);
    const float* qraw = ws + OFF_KVQ + ((long)b * 3 + 2) * 16384;
    float* zc = ws + OFF_Z + ((long)b * 2048 + (long)t * 16) * 1024;
    mcK1(sm, spreo, base + 1048576, n0, flg, [&](int c, int n, float v) {
      zc[(long)c * 1024 + n] = fmaf(cW1, v, cb1 * b1v[n] + qraw[(long)c * 1024 + n] * sminv[c]);
    });
  } else {
    const int id = bid - 640, b = id >> 1, m = 3 + (id & 1);
    const float* sprev = ws + OFF_SPREV + ((long)b * 6 + m) * 16384;
    const float* sprek = ws + OFF_SPREK + ((long)b * 6 + m) * 16384;
    float* base = modBase(ws, b, m);
    const float* w1 = vecp(base, m) + 2048;
    float av[16], ap[16];
#pragma unroll
    for (int c = 0; c < 16; c++) { av[c] = 0.f; ap[c] = 0.f; }
    for (int jj = 0; jj < 4; jj++) {
      const int h = tid + 256 * jj;
      const float w = w1[h];
#pragma unroll
      for (int c = 0; c < 16; c++) {
        av[c] = fmaf(sprev[c * 1024 + h], w, av[c]);
        ap[c] = fmaf(sprek[c * 1024 + h], w, ap[c]);
      }
    }
#pragma unroll
    for (int st = 1; st < 64; st <<= 1)
#pragma unroll
      for (int c = 0; c < 16; c++) {
        av[c] += __shfl_xor(av[c], st);
        ap[c] += __shfl_xor(ap[c], st);
      }
    if ((tid & 63) == 0) {
      const int w4 = tid >> 6;
#pragma unroll
      for (int c = 0; c < 16; c++) { sm4[w4 * 32 + c] = av[c]; sm4[w4 * 32 + 16 + c] = ap[c]; }
    }
    __syncthreads();
    if (tid == 0) {
      const float cW1 = sclOf(ws, sp, b, m, 0), cb1 = sclOf(ws, sp, b, m, 1);
      const float b10 = vecp(base, m)[0];
      float* errP = ws + OFF_ERR + ((long)b * 6 + m) * 16384;
      for (int c = 0; c < 16; c++) {
        const float sv = sm4[c] + sm4[32 + c] + sm4[64 + c] + sm4[96 + c];
        const float sp2 = sm4[16 + c] + sm4[48 + c] + sm4[80 + c] + sm4[112 + c];
        errP[c * 1024] = (fmaf(cW1, sp2, cb1 * b10) - fmaf(cW1, sv, cb1 * b10)) * 0.0625f;
      }
    }
  }
}

// S5: dlp = cW1*(err@W1)*silu_grad(prek). grid 544.
__global__ __launch_bounds__(256) void k_s5(float* ws, int t) {
  __shared__ float sm[2048];
  const int tid = threadIdx.x, bid = blockIdx.x;
  const int sp = (t + 1) & 1;
  if (bid < 512) {
    const int h0 = (bid & 31) * 32, mi = (bid >> 5) & 3, b = bid >> 7;
    const int m = BIGM[mi];
    const int flg = (int)ws[OFF_FLAG];
    float* base = modBase(ws, b, m);
    const float* errP = ws + OFF_ERR + ((long)b * 6 + m) * 16384;
    const float cW1 = sclOf(ws, sp, b, m, 0);
    const float* prek = ws + OFF_PREK + ((long)b * 6 + m) * 16384;
    float* dlp = ws + OFF_DLP + ((long)b * 6 + m) * 16384;
    mcK1t(sm, errP, base + 1048576, h0, flg, [&](int c, int h, float v) {
      const float pre = prek[(long)c * 1024 + h];
      const float sg = sigm(pre);
      dlp[(long)c * 1024 + h] = cW1 * v * (sg * (1.f + pre * (1.f - sg)));
    });
  } else {
    const int e = bid - 512, sub = e & 3, bm = e >> 2, b = bm >> 1, m = 3 + (bm & 1);
    const float cW1 = sclOf(ws, sp, b, m, 0);
    const float* errP = ws + OFF_ERR + ((long)b * 6 + m) * 16384;
    const float* prek = ws + OFF_PREK + ((long)b * 6 + m) * 16384;
    const float* w1 = vecp(modBase(ws, b, m), m) + 2048;
    float* dlp = ws + OFF_DLP + ((long)b * 6 + m) * 16384;
    for (int i = tid; i < 4096; i += 256) {
      const long idx = (long)sub * 4096 + i;
      const int c = (int)(idx >> 10), h = (int)(idx & 1023);
      const float pre = prek[idx];
      const float sg = sigm(pre);
      dlp[idx] = errP[c * 1024] * cW1 * w1[h] * (sg * (1.f + pre * (1.f - sg)));
    }
  }
}

// S6: fused grad + decay-update + sumsq. grid 696.
__global__ __launch_bounds__(256) void k_s6(float* ws, int t) {
  __shared__ float sm[64 * 20 + 8];
  float* slack = sm + 64 * 20;
  const int tid = threadIdx.x, bid = blockIdx.x;
  const int sp = (t + 1) & 1, pc = t & 1;
  if (bid < 640) {
    const bool isW2 = bid < 384;
    int b, m, r0, pslot;
    float* W;
    float4 fac[16];
    const float* tsrc;
    if (isW2) {
      const int bm = bid >> 4;
      b = bm / 6; m = bm % 6; r0 = (bid & 15) * 64;
      W = modBase(ws, b, m);
      pslot = 2;
      tsrc = ws + OFF_DLP + ((long)b * 6 + m) * 16384;
      const float* kraw = ws + OFF_KVQ + ((long)b * 3) * 16384;
#pragma unroll
      for (int c = 0; c < 16; c++) {
        const float inv = 1.f / fmaxf(sqrtf(ws[OFF_RSSQ + pc * 128 + (long)b * 32 + c]), 1e-12f);
        const float4 kk = *(const float4*)(kraw + (long)c * 1024 + tid * 4);
        fac[c].x = kk.x * inv; fac[c].y = kk.y * inv;
        fac[c].z = kk.z * inv; fac[c].w = kk.w * inv;
      }
    } else {
      const int id = bid - 384, bm = id >> 4;
      b = bm >> 2; m = BIGM[bm & 3]; r0 = (id & 15) * 64;
      W = modBase(ws, b, m) + 1048576;
      pslot = 0;
      tsrc = ws + OFF_ERR + ((long)b * 6 + m) * 16384;
      const float* sprek = ws + OFF_SPREK + ((long)b * 6 + m) * 16384;
#pragma unroll
      for (int c = 0; c < 16; c++)
        fac[c] = *(const float4*)(sprek + (long)c * 1024 + tid * 4);
    }
    for (int f = tid; f < 1024; f += 256) {
      const int c = f >> 6, hh = f & 63;
      sm[hh * 20 + c] = tsrc[(long)c * 1024 + r0 + hh];
    }
    __syncthreads();
    const float ea = ws[OFF_EA + b], aa = ws[OFF_EA + 4 + b];
    const float ac = aa * sclOf(ws, sp, b, m, pslot);
    float ss = 0.f;
#pragma unroll 1
    for (int hh = 0; hh < 64; hh++) {
      const float4 q0 = *(const float4*)(sm + hh * 20);
      const float4 q1 = *(const float4*)(sm + hh * 20 + 4);
      const float4 q2 = *(const float4*)(sm + hh * 20 + 8);
      const float4 q3 = *(const float4*)(sm + hh * 20 + 12);
      float4 g = {0.f, 0.f, 0.f, 0.f};
#pragma unroll
      for (int c = 0; c < 16; c++) {
        const float4 qq = c < 4 ? q0 : (c < 8 ? q1 : (c < 12 ? q2 : q3));
        const float dv = (&qq.x)[c & 3];
        g.x = fmaf(dv, fac[c].x, g.x);
        g.y = fmaf(dv, fac[c].y, g.y);
        g.z = fmaf(dv, fac[c].z, g.z);
        g.w = fmaf(dv, fac[c].w, g.w);
      }
      float4* Wp = (float4*)(W + (size_t)(r0 + hh) * 1024 + tid * 4);
      float4 w = *Wp;
      w.x = fmaf(ac, w.x, -ea * g.x);
      w.y = fmaf(ac, w.y, -ea * g.y);
      w.z = fmaf(ac, w.z, -ea * g.z);
      w.w = fmaf(ac, w.w, -ea * g.w);
      *Wp = w;
      ss = fmaf(w.x, w.x, fmaf(w.y, w.y, fmaf(w.z, w.z, fmaf(w.w, w.w, ss))));
    }
    sumsqReduce(ss, slack, ws + OFF_SUMSQ + pc * 96 + sidx(b, m, pslot));
  } else if (bid < 688) {
    const int id = bid - 640;
    const int b = id / 12, r = id % 12, m = r >> 1, which = r & 1;
    const float ea = ws[OFF_EA + b], aa = ws[OFF_EA + 4 + b];
    float* vc = vecp(modBase(ws, b, m), m);
    float ss = 0.f;
    if (which == 0) {
      const int n = DOUTS[m];
      const float* errP = ws + OFF_ERR + ((long)b * 6 + m) * 16384;
      const float ac = aa * sclOf(ws, sp, b, m, 1);
      for (int o = tid; o < n; o += 256) {
        float gs = 0.f;
#pragma unroll
        for (int c = 0; c < 16; c++) gs += errP[c * 1024 + o];
        const float nw = fmaf(ac, vc[o], -ea * gs);
        vc[o] = nw;
        ss = fmaf(nw, nw, ss);
      }
      sumsqReduce(ss, slack, ws + OFF_SUMSQ + pc * 96 + sidx(b, m, 1));
    } else {
      const float* dlpP = ws + OFF_DLP + ((long)b * 6 + m) * 16384;
      const float ac = aa * sclOf(ws, sp, b, m, 3);
      for (int h = tid; h < 1024; h += 256) {
        float gs = 0.f;
#pragma unroll
        for (int c = 0; c < 16; c++) gs += dlpP[c * 1024 + h];
        const float nw = fmaf(ac, vc[1024 + h], -ea * gs);
        vc[1024 + h] = nw;
        ss = fmaf(nw, nw, ss);
      }
      sumsqReduce(ss, slack, ws + OFF_SUMSQ + pc * 96 + sidx(b, m, 3));
    }
  } else {
    const int e2 = bid - 688, b = e2 >> 1, m = 3 + (e2 & 1);
    const float ea = ws[OFF_EA + b], aa = ws[OFF_EA + 4 + b];
    float* vc = vecp(modBase(ws, b, m), m);
    const float* errP = ws + OFF_ERR + ((long)b * 6 + m) * 16384;
    const float* sprek = ws + OFF_SPREK + ((long)b * 6 + m) * 16384;
    const float ac = aa * sclOf(ws, sp, b, m, 0);
    float ss = 0.f;
    for (int h = tid; h < 1024; h += 256) {
      float gs = 0.f;
#pragma unroll
      for (int c = 0; c < 16; c++)
        gs = fmaf(errP[c * 1024], sprek[c * 1024 + h], gs);
      const float nw = fmaf(ac, vc[2048 + h], -ea * gs);
      vc[2048 + h] = nw;
      ss = fmaf(nw, nw, ss);
    }
    sumsqReduce(ss, slack, ws + OFF_SUMSQ + pc * 96 + sidx(b, m, 0));
  }
}

// ============================ epilogue ============================

__global__ __launch_bounds__(256) void k_ln(float* ws, const float* __restrict__ g,
                                            const float* __restrict__ bb) {
  __shared__ float sm[8];
  float* p = ws + OFF_Z + (long)blockIdx.x * 1024;
  const int tid = threadIdx.x;
  float s = 0.f, s2 = 0.f;
  for (int j = tid; j < 1024; j += 256) {
    const float v = p[j];
    s += v;
    s2 = fmaf(v, v, s2);
  }
#pragma unroll
  for (int st = 32; st >= 1; st >>= 1) { s += __shfl_xor(s, st); s2 += __shfl_xor(s2, st); }
  if ((tid & 63) == 0) { sm[tid >> 6] = s; sm[4 + (tid >> 6)] = s2; }
  __syncthreads();
  const float S = sm[0] + sm[1] + sm[2] + sm[3];
  const float S2 = sm[4] + sm[5] + sm[6] + sm[7];
  const float mu = S * (1.f / 1024.f);
  const float var = S2 * (1.f / 1024.f) - mu * mu;
  const float inv = 1.f / sqrtf(var + 1e-5f);
  for (int j = tid; j < 1024; j += 256) {
    p[j] = fmaf((p[j] - mu) * inv, g[j], bb[j]);
  }
}

}  // namespace

extern "C" void kernel_launch(void* const* d_in, const int* in_sizes, int n_in,
                              void* d_out, int out_size, void* d_ws, size_t ws_size,
                              hipStream_t stream) {
  (void)in_sizes; (void)n_in; (void)out_size;
  if (ws_size < (size_t)WS_FLOATS * sizeof(float)) return;
  float* ws = (float*)d_ws;
  InPtrs ip;
  for (int i = 0; i < 31; i++) ip.p[i] = (const float*)d_in[i];

  k_probe<<<1, 64, 0, stream>>>(ws);
  k_p0<<<256, 256, 0, stream>>>(ws, ip);
  k_pc<<<5120, 256, 0, stream>>>(ws, ip);
  k_gbig<<<16384, 256, 0, stream>>>((const float*)d_in[0], (const float*)d_in[25],
                                    (const float*)d_in[26], ws + OFF_Z, ws + OFF_FLAG);

  for (int t = 0; t < 128; t++) {
    k_s1<<<641, 256, 0, stream>>>(ws, t);
    k_s2<<<392, 256, 0, stream>>>(ws, t);
    k_s3<<<896, 256, 0, stream>>>(ws, t);
    k_s4<<<648, 256, 0, stream>>>(ws, t);
    k_s5<<<544, 256, 0, stream>>>(ws, t);
    k_s6<<<696, 256, 0, stream>>>(ws, t);
  }

  k_ln<<<8192, 256, 0, stream>>>(ws, (const float*)d_in[29], (const float*)d_in[30]);
  k_gbig<<<16384, 256, 0, stream>>>(ws + OFF_Z, (const float*)d_in[27],
                                    (const float*)d_in[28], (float*)d_out, ws + OFF_FLAG);
}

// Round 11
// 20630.399 us; speedup vs baseline: 1.3414x; 1.0612x over previous
//
#include <hip/hip_runtime.h>
#include <math.h>

#define DI __device__ __forceinline__

namespace {

typedef unsigned short u16;
typedef unsigned int u32;
typedef __attribute__((ext_vector_type(8))) short bf8;   // 8 bf16
typedef __attribute__((ext_vector_type(4))) float f4;

DI f4 MFB(bf8 a, bf8 b, f4 c) { return __builtin_amdgcn_mfma_f32_16x16x32_bf16(a, b, c, 0, 0, 0); }

constexpr int DOUTS[6] = {1024, 1024, 1024, 1, 1, 1024};
constexpr int BIGM[4] = {0, 1, 2, 5};

constexpr long SZ_BIGM = 2100224, SZ_SMALLM = 1051648;
constexpr long MODOFF[6] = {0, SZ_BIGM, 2 * SZ_BIGM, 3 * SZ_BIGM,
                            3 * SZ_BIGM + SZ_SMALLM, 3 * SZ_BIGM + 2 * SZ_SMALLM};
constexpr long BSTRIDE = 3 * SZ_BIGM + 2 * SZ_SMALLM + SZ_BIGM;

constexpr long OFF_Z     = 0;
constexpr long OFF_STATE = 8388608;
constexpr long OFF_SPRE5 = OFF_STATE + 4 * BSTRIDE;
constexpr long OFF_KVQ   = OFF_SPRE5 + 327680;
constexpr long OFF_SPREV = OFF_KVQ + 196608;
constexpr long OFF_PREK  = OFF_SPREV + 393216;
constexpr long OFF_SPREK = OFF_PREK + 393216;
constexpr long OFF_SPREO = OFF_SPREK + 393216;
constexpr long OFF_ERR   = OFF_SPREO + 65536;
constexpr long OFF_DLP   = OFF_ERR + 393216;
constexpr long OFF_RSSQ  = OFF_DLP + 393216;   // [2][4][2][16] parity
constexpr long OFF_EA    = OFF_RSSQ + 256;     // 8
constexpr long OFF_SUMSQ = OFF_EA + 8;         // [2][96] parity
constexpr long OFF_FLAG  = OFF_SUMSQ + 192;
constexpr long WS_FLOATS = OFF_FLAG + 8;       // ~211.9 MB

struct InPtrs { const float* p[31]; };

DI float* modBase(float* ws, int b, int m) {
  return ws + OFF_STATE + (long)b * BSTRIDE + MODOFF[m];
}
DI float* vecp(float* base, int m) { return base + ((m == 3 || m == 4) ? 1048576 : 2097152); }
DI int sidx(int b, int m, int p) { return ((b * 6 + m) << 2) + p; }
DI float maxnf(int m, int p) {
  switch (p) {
    case 0: return sqrtf((float)(1024 * DOUTS[m]));
    case 1: return sqrtf((float)DOUTS[m]);
    case 2: return 1024.0f;
    default: return 32.0f;
  }
}
DI float sclOf(const float* ws, int sp, int b, int m, int p) {
  const float S = ws[OFF_SUMSQ + sp * 96 + sidx(b, m, p)];
  return fminf(maxnf(m, p) / (sqrtf(S) + 1e-8f), 1.0f);
}
DI float sigm(float x) { return 1.0f / (1.0f + expf(-x)); }
DI float silu(float x) { return x * sigm(x); }
DI u16 f2bf(float x) {
  u32 u = __float_as_uint(x);
  return (u16)((u + 0x7fffu + ((u >> 16) & 1u)) >> 16);
}

DI void sumsqReduce(float ss, float* slack, float* dst) {
#pragma unroll
  for (int st = 32; st >= 1; st >>= 1) ss += __shfl_xor(ss, st);
  const int tid = threadIdx.x;
  if ((tid & 63) == 0) slack[tid >> 6] = ss;
  __syncthreads();
  if (tid == 0) atomicAdd(dst, slack[0] + slack[1] + slack[2] + slack[3]);
  __syncthreads();
}

// 3-plane bf16 split
DI void split3v(const float v[8], bf8& p0, bf8& p1, bf8& p2) {
#pragma unroll
  for (int i = 0; i < 8; i++) {
    const u32 u = __float_as_uint(v[i]);
    const float f0 = __uint_as_float(u & 0xffff0000u);
    const float r1 = v[i] - f0;
    const u32 u1 = __float_as_uint(r1);
    const float f1 = __uint_as_float(u1 & 0xffff0000u);
    const float r2 = r1 - f1;
    p0[i] = (short)(u >> 16);
    p1[i] = (short)(u1 >> 16);
    p2[i] = (short)f2bf(r2);
  }
}
DI void split3p(const float* p, bf8& p0, bf8& p1, bf8& p2) {
  const float4 a = *(const float4*)p, b = *(const float4*)(p + 4);
  const float v[8] = {a.x, a.y, a.z, a.w, b.x, b.y, b.z, b.w};
  split3v(v, p0, p1, p2);
}

__global__ void k_probe(float* ws) {
  const int l = threadIdx.x, cl = l & 15, kq = l >> 4;
  bf8 af, bf_;
#pragma unroll
  for (int i = 0; i < 8; i++) { af[i] = 0; bf_[i] = 0; }
  if (kq == 0) {
    af[0] = (short)f2bf((float)(cl + 1));
    bf_[0] = (short)f2bf((float)(128 * (cl + 1)));
  }
  f4 d = MFB(af, bf_, f4{0.f, 0.f, 0.f, 0.f});
  bool m0 = true, m1 = true;
#pragma unroll
  for (int r = 0; r < 4; r++) {
    m0 = m0 && (d[r] == (float)((kq * 4 + r + 1) * 128 * (cl + 1)));
    m1 = m1 && (d[r] == (float)((cl + 1) * 128 * (kq * 4 + r + 1)));
  }
  const unsigned long long b0 = __ballot(m0), b1 = __ballot(m1);
  if (l == 0) ws[OFF_FLAG] = (b0 == ~0ull) ? 0.f : ((b1 == ~0ull) ? 1.f : 0.f);
}

// ============ 8-wave 64-col K-split cores (512 threads) ============
// Y[c<16][n0..n0+64) = sum_k X[c][k]*W[n][k]; wave g owns K in [g*128,(g+1)*128).
template <class EF>
DI void mcK1w(float* sm, const float* __restrict__ X, const float* W,
              int n0, int flg, EF&& ef) {
  const int tid = threadIdx.x, g = tid >> 6, l = tid & 63, cl = l & 15, kq = l >> 4;
  f4 acc[4];
#pragma unroll
  for (int s = 0; s < 4; s++) acc[s] = f4{0.f, 0.f, 0.f, 0.f};
  const float* Xr = X + (long)cl * 1024 + g * 128 + kq * 8;
  const float* Wr = W + (long)(n0 + cl) * 1024 + g * 128 + kq * 8;
#pragma unroll 2
  for (int ch = 0; ch < 4; ch++) {
    bf8 x0, x1, x2;
    split3p(Xr + ch * 32, x0, x1, x2);
#pragma unroll
    for (int s = 0; s < 4; s++) {
      bf8 w0, w1, w2;
      split3p(Wr + (long)s * 16384 + ch * 32, w0, w1, w2);
      acc[s] = MFB(x2, w0, acc[s]); acc[s] = MFB(x1, w1, acc[s]); acc[s] = MFB(x0, w2, acc[s]);
      acc[s] = MFB(x1, w0, acc[s]); acc[s] = MFB(x0, w1, acc[s]); acc[s] = MFB(x0, w0, acc[s]);
    }
  }
#pragma unroll
  for (int s = 0; s < 4; s++) *(f4*)(sm + (g * 4 + s) * 256 + l * 4) = acc[s];
  __syncthreads();
#pragma unroll
  for (int i = 0; i < 2; i++) {
    const int idx = tid * 2 + i, s = idx >> 8, pos = idx & 255;
    float v = 0.f;
#pragma unroll
    for (int gg = 0; gg < 8; gg++) v += sm[(gg * 4 + s) * 256 + pos];
    const int le = pos >> 2, re = pos & 3;
    const int ccl = le & 15, ckq = le >> 4;
    const int c = flg ? ccl : ckq * 4 + re;
    const int nb = flg ? ckq * 4 + re : ccl;
    ef(c, n0 + s * 16 + nb, v);
  }
}

// dual-X variant: two X streams share one W pass. sm = 16384 floats.
template <class EF>
DI void mcK2w(float* sm, const float* __restrict__ X1, const float* __restrict__ X2,
              const float* W, int n0, int flg, EF&& ef) {
  const int tid = threadIdx.x, g = tid >> 6, l = tid & 63, cl = l & 15, kq = l >> 4;
  f4 a1[4], a2[4];
#pragma unroll
  for (int s = 0; s < 4; s++) { a1[s] = f4{0.f, 0.f, 0.f, 0.f}; a2[s] = f4{0.f, 0.f, 0.f, 0.f}; }
  const float* X1r = X1 + (long)cl * 1024 + g * 128 + kq * 8;
  const float* X2r = X2 + (long)cl * 1024 + g * 128 + kq * 8;
  const float* Wr = W + (long)(n0 + cl) * 1024 + g * 128 + kq * 8;
#pragma unroll 2
  for (int ch = 0; ch < 4; ch++) {
    bf8 x0, x1, x2, y0, y1, y2;
    split3p(X1r + ch * 32, x0, x1, x2);
    split3p(X2r + ch * 32, y0, y1, y2);
#pragma unroll
    for (int s = 0; s < 4; s++) {
      bf8 w0, w1, w2;
      split3p(Wr + (long)s * 16384 + ch * 32, w0, w1, w2);
      a1[s] = MFB(x2, w0, a1[s]); a1[s] = MFB(x1, w1, a1[s]); a1[s] = MFB(x0, w2, a1[s]);
      a1[s] = MFB(x1, w0, a1[s]); a1[s] = MFB(x0, w1, a1[s]); a1[s] = MFB(x0, w0, a1[s]);
      a2[s] = MFB(y2, w0, a2[s]); a2[s] = MFB(y1, w1, a2[s]); a2[s] = MFB(y0, w2, a2[s]);
      a2[s] = MFB(y1, w0, a2[s]); a2[s] = MFB(y0, w1, a2[s]); a2[s] = MFB(y0, w0, a2[s]);
    }
  }
#pragma unroll
  for (int s = 0; s < 4; s++) {
    *(f4*)(sm + (g * 4 + s) * 256 + l * 4) = a1[s];
    *(f4*)(sm + 8192 + (g * 4 + s) * 256 + l * 4) = a2[s];
  }
  __syncthreads();
#pragma unroll
  for (int i = 0; i < 2; i++) {
    const int idx = tid * 2 + i, s = idx >> 8, pos = idx & 255;
    float v1 = 0.f, v2 = 0.f;
#pragma unroll
    for (int gg = 0; gg < 8; gg++) {
      v1 += sm[(gg * 4 + s) * 256 + pos];
      v2 += sm[8192 + (gg * 4 + s) * 256 + pos];
    }
    const int le = pos >> 2, re = pos & 3;
    const int ccl = le & 15, ckq = le >> 4;
    const int c = flg ? ccl : ckq * 4 + re;
    const int nb = flg ? ckq * 4 + re : ccl;
    ef(c, n0 + s * 16 + nb, v1, v2);
  }
}

// transposed-W (s5): G[c][h] = sum_o E[c][o]*W1[o][h].
template <class EF>
DI void mcK1tw(float* sm, const float* __restrict__ E, const float* W1,
               int h0, int flg, EF&& ef) {
  const int tid = threadIdx.x, g = tid >> 6, l = tid & 63, cl = l & 15, kq = l >> 4;
  f4 acc[4];
#pragma unroll
  for (int s = 0; s < 4; s++) acc[s] = f4{0.f, 0.f, 0.f, 0.f};
  const float* Er = E + (long)cl * 1024 + g * 128 + kq * 8;
  const float* Wc = W1 + (long)(g * 128 + kq * 8) * 1024 + h0 + cl;
#pragma unroll 2
  for (int ch = 0; ch < 4; ch++) {
    bf8 x0, x1, x2;
    split3p(Er + ch * 32, x0, x1, x2);
#pragma unroll
    for (int s = 0; s < 4; s++) {
      float v[8];
#pragma unroll
      for (int i = 0; i < 8; i++) v[i] = Wc[(long)(ch * 32 + i) * 1024 + s * 16];
      bf8 w0, w1, w2;
      split3v(v, w0, w1, w2);
      acc[s] = MFB(x2, w0, acc[s]); acc[s] = MFB(x1, w1, acc[s]); acc[s] = MFB(x0, w2, acc[s]);
      acc[s] = MFB(x1, w0, acc[s]); acc[s] = MFB(x0, w1, acc[s]); acc[s] = MFB(x0, w0, acc[s]);
    }
  }
#pragma unroll
  for (int s = 0; s < 4; s++) *(f4*)(sm + (g * 4 + s) * 256 + l * 4) = acc[s];
  __syncthreads();
#pragma unroll
  for (int i = 0; i < 2; i++) {
    const int idx = tid * 2 + i, s = idx >> 8, pos = idx & 255;
    float v = 0.f;
#pragma unroll
    for (int gg = 0; gg < 8; gg++) v += sm[(gg * 4 + s) * 256 + pos];
    const int le = pos >> 2, re = pos & 3;
    const int ccl = le & 15, ckq = le >> 4;
    const int c = flg ? ccl : ckq * 4 + re;
    const int hb = flg ? ckq * 4 + re : ccl;
    ef(c, h0 + s * 16 + hb, v);
  }
}

// ============ legacy 4-wave 32-col core (s2 only; R10-verified) ============
template <class EF>
DI void mcK1o(float* sm, const float* __restrict__ X, const float* W,
              int n0, int flg, EF&& ef) {
  const int tid = threadIdx.x, g = tid >> 6, l = tid & 63, cl = l & 15, kq = l >> 4;
  f4 a0 = {0.f, 0.f, 0.f, 0.f}, a1 = {0.f, 0.f, 0.f, 0.f};
  const float* Xr = X + (long)cl * 1024 + g * 256 + kq * 8;
  const float* Wr0 = W + (long)(n0 + cl) * 1024 + g * 256 + kq * 8;
  const float* Wr1 = Wr0 + 16 * 1024;
#pragma unroll 2
  for (int ch = 0; ch < 8; ch++) {
    bf8 x0, x1, x2, w0, w1, w2;
    split3p(Xr + ch * 32, x0, x1, x2);
    split3p(Wr0 + ch * 32, w0, w1, w2);
    a0 = MFB(x2, w0, a0); a0 = MFB(x1, w1, a0); a0 = MFB(x0, w2, a0);
    a0 = MFB(x1, w0, a0); a0 = MFB(x0, w1, a0); a0 = MFB(x0, w0, a0);
    split3p(Wr1 + ch * 32, w0, w1, w2);
    a1 = MFB(x2, w0, a1); a1 = MFB(x1, w1, a1); a1 = MFB(x0, w2, a1);
    a1 = MFB(x1, w0, a1); a1 = MFB(x0, w1, a1); a1 = MFB(x0, w0, a1);
  }
  *(f4*)(sm + g * 256 + l * 4) = a0;
  *(f4*)(sm + 1024 + g * 256 + l * 4) = a1;
  __syncthreads();
  const int le = tid >> 2, re = tid & 3;
  const int ccl = le & 15, ckq = le >> 4;
  const int c = flg ? ccl : ckq * 4 + re;
  const int nb = flg ? ckq * 4 + re : ccl;
#pragma unroll
  for (int half = 0; half < 2; half++) {
    const float v = sm[half * 1024 + le * 4 + re] + sm[half * 1024 + 256 + le * 4 + re] +
                    sm[half * 1024 + 512 + le * 4 + re] + sm[half * 1024 + 768 + le * 4 + re];
    ef(c, n0 + half * 16 + nb, v);
  }
}

// ============================ prologue ============================

__global__ __launch_bounds__(256) void k_p0(float* ws, InPtrs in) {
  const long i = threadIdx.x + (long)blockIdx.x * 256;
  if (i < 256) { ws[OFF_RSSQ + i] = 0.f; return; }
  if (i < 448) { ws[OFF_SUMSQ + (i - 256)] = 0.f; return; }
  if (i < 456) { ws[OFF_EA + (i - 448)] = 0.f; return; }
  const long j = i - 456;
  if (j < 24 * 2048) {
    const int bm = (int)(j >> 11), q = (int)(j & 2047);
    const int b = bm / 6, m = bm % 6;
    float* vc = vecp(modBase(ws, b, m), m);
    if (q < 1024) { if (q < DOUTS[m]) vc[q] = in.p[2 + 4 * m][q]; }
    else vc[1024 + (q - 1024)] = in.p[4 + 4 * m][q - 1024];
    return;
  }
  const long j2 = j - 49152;
  if (j2 < 8192) {
    const int e = (int)(j2 >> 10), b = e >> 1, m = 3 + (e & 1);
    const int h = (int)(j2 & 1023);
    vecp(modBase(ws, b, m), m)[2048 + h] = in.p[1 + 4 * m][h];
  }
}

__global__ __launch_bounds__(256) void k_pc(float* ws, InPtrs in) {
  const int bid = blockIdx.x, job = bid >> 9, sub = bid & 511;
  const long e0 = (long)sub * 2048 + threadIdx.x * 8;
  int m; bool w1;
  if (job < 6) { m = job; w1 = false; }
  else { m = BIGM[job - 6]; w1 = true; }
  const float* src = in.p[(w1 ? 1 : 3) + 4 * m];
  const float4 a = *(const float4*)(src + e0);
  const float4 b4 = *(const float4*)(src + e0 + 4);
#pragma unroll
  for (int q = 0; q < 4; q++) {
    float* dst = modBase(ws, q, m) + (w1 ? 1048576 : 0);
    *(float4*)(dst + e0) = a;
    *(float4*)(dst + e0 + 4) = b4;
  }
}

// big GEMM v2: 128-row x 64-col blocks; 8 waves x 16 private rows; no LDS.
__global__ __launch_bounds__(512) void k_gbig2(const float* __restrict__ X,
                                               const float* A,
                                               const float* __restrict__ bias,
                                               float* __restrict__ Y,
                                               const float* flagp) {
  const int bid = blockIdx.x, nb = bid & 15;
  const long rbg = bid >> 4;
  const int tid = threadIdx.x, g = tid >> 6, l = tid & 63, cl = l & 15, kq = l >> 4;
  const int flg = (int)flagp[0];
  const int n0 = nb * 64;
  const long row0 = rbg * 128 + g * 16;
  f4 acc[4];
#pragma unroll
  for (int s = 0; s < 4; s++) acc[s] = f4{0.f, 0.f, 0.f, 0.f};
  const float* Xr = X + (row0 + cl) * 1024 + kq * 8;
  const float* Wr = A + (long)(n0 + cl) * 1024 + kq * 8;
#pragma unroll 2
  for (int ch = 0; ch < 32; ch++) {
    bf8 x0, x1, x2;
    split3p(Xr + ch * 32, x0, x1, x2);
#pragma unroll
    for (int s = 0; s < 4; s++) {
      bf8 w0, w1, w2;
      split3p(Wr + (long)s * 16384 + ch * 32, w0, w1, w2);
      acc[s] = MFB(x2, w0, acc[s]); acc[s] = MFB(x1, w1, acc[s]); acc[s] = MFB(x0, w2, acc[s]);
      acc[s] = MFB(x1, w0, acc[s]); acc[s] = MFB(x0, w1, acc[s]); acc[s] = MFB(x0, w0, acc[s]);
    }
  }
#pragma unroll
  for (int s = 0; s < 4; s++)
#pragma unroll
    for (int r = 0; r < 4; r++) {
      const int c = flg ? cl : kq * 4 + r;
      const int n = n0 + s * 16 + (flg ? kq * 4 + r : cl);
      Y[(row0 + c) * 1024 + n] = acc[s][r] + bias[n];
    }
}

// ============================ per-step ============================

// S1: spre5 = silu(cW2*(z @ W2^T) + cb2*b2). grid 321x512 (last block = parity zero).
__global__ __launch_bounds__(512) void k_s1(float* ws, int t) {
  __shared__ float sm[8192];
  const int bid = blockIdx.x, tid = threadIdx.x;
  if (bid == 320) {
    const int pc = t & 1;
    if (tid < 128) ws[OFF_RSSQ + pc * 128 + tid] = 0.f;
    else if (tid < 224) ws[OFF_SUMSQ + pc * 96 + (tid - 128)] = 0.f;
    return;
  }
  const int n0 = (bid & 15) * 64, m = (bid >> 4) % 5, b = bid / 80;
  const int flg = (int)ws[OFF_FLAG];
  const int sp = (t + 1) & 1;
  const float* zc = ws + OFF_Z + ((long)b * 2048 + (long)t * 16) * 1024;
  float* base = modBase(ws, b, m);
  const float cW2 = sclOf(ws, sp, b, m, 2), cb2 = sclOf(ws, sp, b, m, 3);
  const float* b2v = vecp(base, m) + 1024;
  float* Y = ws + OFF_SPRE5 + ((long)b * 5 + m) * 16384;
  mcK1w(sm, zc, base, n0, flg, [&](int c, int n, float v) {
    Y[(long)c * 1024 + n] = silu(fmaf(cW2, v, cb2 * b2v[n]));
  });
}

// S2 (legacy 4-wave 32-col): kvq + rssq + heads. grid 392x256.
__global__ __launch_bounds__(256) void k_s2(float* ws, int t) {
  __shared__ float sm[2048 + 16 + 64];
  float* smr = sm + 2048;
  float* sm2 = sm + 2064;
  const int tid = threadIdx.x, bid = blockIdx.x;
  const int sp = (t + 1) & 1, pc = t & 1;
  if (bid < 384) {
    const int n0 = (bid & 31) * 32, m = (bid >> 5) % 3, b = bid / 96;
    const int flg = (int)ws[OFF_FLAG];
    if (tid < 16) smr[tid] = 0.f;
    const float* spre = ws + OFF_SPRE5 + ((long)b * 5 + m) * 16384;
    float* base = modBase(ws, b, m);
    const float* zc = ws + OFF_Z + ((long)b * 2048 + (long)t * 16) * 1024;
    const float cW1 = sclOf(ws, sp, b, m, 0), cb1 = sclOf(ws, sp, b, m, 1);
    const float* b1v = vecp(base, m);
    float* out = ws + OFF_KVQ + ((long)b * 3 + m) * 16384;
    const bool sq = (m != 1);
    mcK1o(sm, spre, base + 1048576, n0, flg, [&](int c, int n, float v) {
      const float val = fmaf(cW1, v, fmaf(cb1, b1v[n], zc[(long)c * 1024 + n]));
      out[(long)c * 1024 + n] = val;
      if (sq) atomicAdd(&smr[c], val * val);
    });
    __syncthreads();
    if (sq && tid < 16)
      atomicAdd(ws + OFF_RSSQ + pc * 128 + (long)b * 32 + (m == 0 ? 0 : 16) + tid,
                smr[tid]);
  } else {
    const int e = bid - 384, b = e >> 1, m = 3 + (e & 1);
    const float* spre = ws + OFF_SPRE5 + ((long)b * 5 + m) * 16384;
    float* base = modBase(ws, b, m);
    const float* w1 = vecp(base, m) + 2048;
    float av[16];
#pragma unroll
    for (int c = 0; c < 16; c++) av[c] = 0.f;
    for (int jj = 0; jj < 4; jj++) {
      const int h = tid + 256 * jj;
      const float w = w1[h];
#pragma unroll
      for (int c = 0; c < 16; c++) av[c] = fmaf(spre[c * 1024 + h], w, av[c]);
    }
#pragma unroll
    for (int st = 1; st < 64; st <<= 1)
#pragma unroll
      for (int c = 0; c < 16; c++) av[c] += __shfl_xor(av[c], st);
    if ((tid & 63) == 0) {
      const int w4 = tid >> 6;
#pragma unroll
      for (int c = 0; c < 16; c++) sm2[w4 * 16 + c] = av[c];
    }
    __syncthreads();
    if (tid == 0) {
      const float cW1 = sclOf(ws, sp, b, m, 0), cb1 = sclOf(ws, sp, b, m, 1);
      const float b10 = vecp(base, m)[0];
      float s = 0.f;
      for (int c = 0; c < 16; c++) {
        const float tot = sm2[c] + sm2[16 + c] + sm2[32 + c] + sm2[48 + c];
        s += sigm(fmaf(cW1, tot, cb1 * b10));
      }
      ws[OFF_EA + ((m == 3) ? 0 : 4) + b] = s * 0.0625f;
    }
  }
}

// S3: dual (v,k)@W2^T -> sprev/prek/sprek ; q@memW2 -> spreo. grid 448x512.
__global__ __launch_bounds__(512) void k_s3(float* ws, int t) {
  __shared__ float sm[16384 + 16];
  float* sminv = sm + 16384;
  const int bid = blockIdx.x, tid = threadIdx.x;
  const int flg = (int)ws[OFF_FLAG];
  const int sp = (t + 1) & 1, pc = t & 1;
  if (bid < 384) {
    const int n0 = (bid & 15) * 64, m = (bid >> 4) % 6, b = bid / 96;
    if (tid < 16)
      sminv[tid] = 1.f / fmaxf(sqrtf(ws[OFF_RSSQ + pc * 128 + (long)b * 32 + tid]), 1e-12f);
    const float* vX = ws + OFF_KVQ + ((long)b * 3 + 1) * 16384;
    const float* kX = ws + OFF_KVQ + ((long)b * 3 + 0) * 16384;
    float* base = modBase(ws, b, m);
    const float cW2 = sclOf(ws, sp, b, m, 2), cb2 = sclOf(ws, sp, b, m, 3);
    const float* b2v = vecp(base, m) + 1024;
    float* Ysv = ws + OFF_SPREV + ((long)b * 6 + m) * 16384;
    float* Yk = ws + OFF_PREK + ((long)b * 6 + m) * 16384;
    float* Ysk = ws + OFF_SPREK + ((long)b * 6 + m) * 16384;
    mcK2w(sm, vX, kX, base, n0, flg, [&](int c, int n, float v1, float v2) {
      const float bb = cb2 * b2v[n];
      Ysv[(long)c * 1024 + n] = silu(fmaf(cW2, v1, bb));
      const float pk = fmaf(cW2 * sminv[c], v2, bb);
      Yk[(long)c * 1024 + n] = pk;
      Ysk[(long)c * 1024 + n] = silu(pk);
    });
  } else {
    const int id = bid - 384, n0 = (id & 15) * 64, b = id >> 4;
    if (tid < 16)
      sminv[tid] = 1.f / fmaxf(sqrtf(ws[OFF_RSSQ + pc * 128 + (long)b * 32 + 16 + tid]), 1e-12f);
    const float* qX = ws + OFF_KVQ + ((long)b * 3 + 2) * 16384;
    float* base = modBase(ws, b, 5);
    const float cW2 = sclOf(ws, sp, b, 5, 2), cb2 = sclOf(ws, sp, b, 5, 3);
    const float* b2v = vecp(base, 5) + 1024;
    float* Y = ws + OFF_SPREO + (long)b * 16384;
    mcK1w(sm, qX, base, n0, flg, [&](int c, int n, float v) {
      Y[(long)c * 1024 + n] = silu(fmaf(cW2 * sminv[c], v, cb2 * b2v[n]));
    });
  }
}

// S4: dual (sprev,sprek)@W1^T -> err ; spreo@memW1 -> z ; heads. grid 328x512.
__global__ __launch_bounds__(512) void k_s4(float* ws, int t) {
  __shared__ float sm[16384 + 16 + 256];
  float* sminv = sm + 16384;
  float* sm4 = sm + 16400;
  const int tid = threadIdx.x, bid = blockIdx.x;
  const int sp = (t + 1) & 1, pc = t & 1;
  if (bid < 256) {
    const int n0 = (bid & 15) * 64, mi = (bid >> 4) & 3, b = bid >> 6;
    const int m = BIGM[mi];
    const int flg = (int)ws[OFF_FLAG];
    if (tid < 16)
      sminv[tid] = 1.f / fmaxf(sqrtf(ws[OFF_RSSQ + pc * 128 + (long)b * 32 + tid]), 1e-12f);
    const float* sprev = ws + OFF_SPREV + ((long)b * 6 + m) * 16384;
    const float* sprek = ws + OFF_SPREK + ((long)b * 6 + m) * 16384;
    float* base = modBase(ws, b, m);
    const float cW1 = sclOf(ws, sp, b, m, 0), cb1 = sclOf(ws, sp, b, m, 1);
    const float* b1v = vecp(base, m);
    const float* vraw = ws + OFF_KVQ + ((long)b * 3 + 1) * 16384;
    const float* kraw = ws + OFF_KVQ + ((long)b * 3 + 0) * 16384;
    float* errP = ws + OFF_ERR + ((long)b * 6 + m) * 16384;
    mcK2w(sm, sprev, sprek, base + 1048576, n0, flg, [&](int c, int n, float v1, float v2) {
      const float bbb = cb1 * b1v[n];
      const float vh = fmaf(cW1, v1, bbb + vraw[(long)c * 1024 + n]);
      const float pr = fmaf(cW1, v2, bbb + kraw[(long)c * 1024 + n] * sminv[c]);
      errP[(long)c * 1024 + n] = (pr - vh) * 0.0625f;
    });
  } else if (bid < 320) {
    const int id = bid - 256, n0 = (id & 15) * 64, b = id >> 4;
    const int flg = (int)ws[OFF_FLAG];
    if (tid < 16)
      sminv[tid] = 1.f / fmaxf(sqrtf(ws[OFF_RSSQ + pc * 128 + (long)b * 32 + 16 + tid]), 1e-12f);
    const float* spreo = ws + OFF_SPREO + (long)b * 16384;
    float* base = modBase(ws, b, 5);
    const float cW1 = sclOf(ws, sp, b, 5, 0), cb1 = sclOf(ws, sp, b, 5, 1);
    const float* b1v = vecp(base, 5);
    const float* qraw = ws + OFF_KVQ + ((long)b * 3 + 2) * 16384;
    float* zc = ws + OFF_Z + ((long)b * 2048 + (long)t * 16) * 1024;
    mcK1w(sm, spreo, base + 1048576, n0, flg, [&](int c, int n, float v) {
      zc[(long)c * 1024 + n] = fmaf(cW1, v, cb1 * b1v[n] + qraw[(long)c * 1024 + n] * sminv[c]);
    });
  } else {
    const int id = bid - 320, b = id >> 1, m = 3 + (id & 1);
    const float* sprev = ws + OFF_SPREV + ((long)b * 6 + m) * 16384;
    const float* sprek = ws + OFF_SPREK + ((long)b * 6 + m) * 16384;
    float* base = modBase(ws, b, m);
    const float* w1 = vecp(base, m) + 2048;
    float av[16], ap[16];
#pragma unroll
    for (int c = 0; c < 16; c++) { av[c] = 0.f; ap[c] = 0.f; }
    for (int jj = 0; jj < 2; jj++) {
      const int h = tid + 512 * jj;
      const float w = w1[h];
#pragma unroll
      for (int c = 0; c < 16; c++) {
        av[c] = fmaf(sprev[c * 1024 + h], w, av[c]);
        ap[c] = fmaf(sprek[c * 1024 + h], w, ap[c]);
      }
    }
#pragma unroll
    for (int st = 1; st < 64; st <<= 1)
#pragma unroll
      for (int c = 0; c < 16; c++) {
        av[c] += __shfl_xor(av[c], st);
        ap[c] += __shfl_xor(ap[c], st);
      }
    if ((tid & 63) == 0) {
      const int w8 = tid >> 6;
#pragma unroll
      for (int c = 0; c < 16; c++) { sm4[w8 * 32 + c] = av[c]; sm4[w8 * 32 + 16 + c] = ap[c]; }
    }
    __syncthreads();
    if (tid == 0) {
      const float cW1 = sclOf(ws, sp, b, m, 0), cb1 = sclOf(ws, sp, b, m, 1);
      const float b10 = vecp(base, m)[0];
      float* errP = ws + OFF_ERR + ((long)b * 6 + m) * 16384;
      for (int c = 0; c < 16; c++) {
        float sv = 0.f, sp2 = 0.f;
        for (int w8 = 0; w8 < 8; w8++) { sv += sm4[w8 * 32 + c]; sp2 += sm4[w8 * 32 + 16 + c]; }
        errP[c * 1024] = (fmaf(cW1, sp2, cb1 * b10) - fmaf(cW1, sv, cb1 * b10)) * 0.0625f;
      }
    }
  }
}

// S5: dlp = cW1*(err@W1)*silu_grad(prek). grid 288x512.
__global__ __launch_bounds__(512) void k_s5(float* ws, int t) {
  __shared__ float sm[8192];
  const int tid = threadIdx.x, bid = blockIdx.x;
  const int sp = (t + 1) & 1;
  if (bid < 256) {
    const int h0 = (bid & 15) * 64, mi = (bid >> 4) & 3, b = bid >> 6;
    const int m = BIGM[mi];
    const int flg = (int)ws[OFF_FLAG];
    float* base = modBase(ws, b, m);
    const float* errP = ws + OFF_ERR + ((long)b * 6 + m) * 16384;
    const float cW1 = sclOf(ws, sp, b, m, 0);
    const float* prek = ws + OFF_PREK + ((long)b * 6 + m) * 16384;
    float* dlp = ws + OFF_DLP + ((long)b * 6 + m) * 16384;
    mcK1tw(sm, errP, base + 1048576, h0, flg, [&](int c, int h, float v) {
      const float pre = prek[(long)c * 1024 + h];
      const float sg = sigm(pre);
      dlp[(long)c * 1024 + h] = cW1 * v * (sg * (1.f + pre * (1.f - sg)));
    });
  } else {
    const int e = bid - 256, sub = e & 3, bm = e >> 2, b = bm >> 1, m = 3 + (bm & 1);
    const float cW1 = sclOf(ws, sp, b, m, 0);
    const float* errP = ws + OFF_ERR + ((long)b * 6 + m) * 16384;
    const float* prek = ws + OFF_PREK + ((long)b * 6 + m) * 16384;
    const float* w1 = vecp(modBase(ws, b, m), m) + 2048;
    float* dlp = ws + OFF_DLP + ((long)b * 6 + m) * 16384;
    for (int i = tid; i < 4096; i += 512) {
      const long idx = (long)sub * 4096 + i;
      const int c = (int)(idx >> 10), h = (int)(idx & 1023);
      const float pre = prek[idx];
      const float sg = sigm(pre);
      dlp[idx] = errP[c * 1024] * cW1 * w1[h] * (sg * (1.f + pre * (1.f - sg)));
    }
  }
}

// S6: fused grad + decay-update + sumsq. grid 696x256 (unchanged).
__global__ __launch_bounds__(256) void k_s6(float* ws, int t) {
  __shared__ float sm[64 * 20 + 8];
  float* slack = sm + 64 * 20;
  const int tid = threadIdx.x, bid = blockIdx.x;
  const int sp = (t + 1) & 1, pc = t & 1;
  if (bid < 640) {
    const bool isW2 = bid < 384;
    int b, m, r0, pslot;
    float* W;
    float4 fac[16];
    const float* tsrc;
    if (isW2) {
      const int bm = bid >> 4;
      b = bm / 6; m = bm % 6; r0 = (bid & 15) * 64;
      W = modBase(ws, b, m);
      pslot = 2;
      tsrc = ws + OFF_DLP + ((long)b * 6 + m) * 16384;
      const float* kraw = ws + OFF_KVQ + ((long)b * 3) * 16384;
#pragma unroll
      for (int c = 0; c < 16; c++) {
        const float inv = 1.f / fmaxf(sqrtf(ws[OFF_RSSQ + pc * 128 + (long)b * 32 + c]), 1e-12f);
        const float4 kk = *(const float4*)(kraw + (long)c * 1024 + tid * 4);
        fac[c].x = kk.x * inv; fac[c].y = kk.y * inv;
        fac[c].z = kk.z * inv; fac[c].w = kk.w * inv;
      }
    } else {
      const int id = bid - 384, bm = id >> 4;
      b = bm >> 2; m = BIGM[bm & 3]; r0 = (id & 15) * 64;
      W = modBase(ws, b, m) + 1048576;
      pslot = 0;
      tsrc = ws + OFF_ERR + ((long)b * 6 + m) * 16384;
      const float* sprek = ws + OFF_SPREK + ((long)b * 6 + m) * 16384;
#pragma unroll
      for (int c = 0; c < 16; c++)
        fac[c] = *(const float4*)(sprek + (long)c * 1024 + tid * 4);
    }
    for (int f = tid; f < 1024; f += 256) {
      const int c = f >> 6, hh = f & 63;
      sm[hh * 20 + c] = tsrc[(long)c * 1024 + r0 + hh];
    }
    __syncthreads();
    const float ea = ws[OFF_EA + b], aa = ws[OFF_EA + 4 + b];
    const float ac = aa * sclOf(ws, sp, b, m, pslot);
    float ss = 0.f;
#pragma unroll 1
    for (int hh = 0; hh < 64; hh++) {
      const float4 q0 = *(const float4*)(sm + hh * 20);
      const float4 q1 = *(const float4*)(sm + hh * 20 + 4);
      const float4 q2 = *(const float4*)(sm + hh * 20 + 8);
      const float4 q3 = *(const float4*)(sm + hh * 20 + 12);
      float4 g = {0.f, 0.f, 0.f, 0.f};
#pragma unroll
      for (int c = 0; c < 16; c++) {
        const float4 qq = c < 4 ? q0 : (c < 8 ? q1 : (c < 12 ? q2 : q3));
        const float dv = (&qq.x)[c & 3];
        g.x = fmaf(dv, fac[c].x, g.x);
        g.y = fmaf(dv, fac[c].y, g.y);
        g.z = fmaf(dv, fac[c].z, g.z);
        g.w = fmaf(dv, fac[c].w, g.w);
      }
      float4* Wp = (float4*)(W + (size_t)(r0 + hh) * 1024 + tid * 4);
      float4 w = *Wp;
      w.x = fmaf(ac, w.x, -ea * g.x);
      w.y = fmaf(ac, w.y, -ea * g.y);
      w.z = fmaf(ac, w.z, -ea * g.z);
      w.w = fmaf(ac, w.w, -ea * g.w);
      *Wp = w;
      ss = fmaf(w.x, w.x, fmaf(w.y, w.y, fmaf(w.z, w.z, fmaf(w.w, w.w, ss))));
    }
    sumsqReduce(ss, slack, ws + OFF_SUMSQ + pc * 96 + sidx(b, m, pslot));
  } else if (bid < 688) {
    const int id = bid - 640;
    const int b = id / 12, r = id % 12, m = r >> 1, which = r & 1;
    const float ea = ws[OFF_EA + b], aa = ws[OFF_EA + 4 + b];
    float* vc = vecp(modBase(ws, b, m), m);
    float ss = 0.f;
    if (which == 0) {
      const int n = DOUTS[m];
      const float* errP = ws + OFF_ERR + ((long)b * 6 + m) * 16384;
      const float ac = aa * sclOf(ws, sp, b, m, 1);
      for (int o = tid; o < n; o += 256) {
        float gs = 0.f;
#pragma unroll
        for (int c = 0; c < 16; c++) gs += errP[c * 1024 + o];
        const float nw = fmaf(ac, vc[o], -ea * gs);
        vc[o] = nw;
        ss = fmaf(nw, nw, ss);
      }
      sumsqReduce(ss, slack, ws + OFF_SUMSQ + pc * 96 + sidx(b, m, 1));
    } else {
      const float* dlpP = ws + OFF_DLP + ((long)b * 6 + m) * 16384;
      const float ac = aa * sclOf(ws, sp, b, m, 3);
      for (int h = tid; h < 1024; h += 256) {
        float gs = 0.f;
#pragma unroll
        for (int c = 0; c < 16; c++) gs += dlpP[c * 1024 + h];
        const float nw = fmaf(ac, vc[1024 + h], -ea * gs);
        vc[1024 + h] = nw;
        ss = fmaf(nw, nw, ss);
      }
      sumsqReduce(ss, slack, ws + OFF_SUMSQ + pc * 96 + sidx(b, m, 3));
    }
  } else {
    const int e2 = bid - 688, b = e2 >> 1, m = 3 + (e2 & 1);
    const float ea = ws[OFF_EA + b], aa = ws[OFF_EA + 4 + b];
    float* vc = vecp(modBase(ws, b, m), m);
    const float* errP = ws + OFF_ERR + ((long)b * 6 + m) * 16384;
    const float* sprek = ws + OFF_SPREK + ((long)b * 6 + m) * 16384;
    const float ac = aa * sclOf(ws, sp, b, m, 0);
    float ss = 0.f;
    for (int h = tid; h < 1024; h += 256) {
      float gs = 0.f;
#pragma unroll
      for (int c = 0; c < 16; c++)
        gs = fmaf(errP[c * 1024], sprek[c * 1024 + h], gs);
      const float nw = fmaf(ac, vc[2048 + h], -ea * gs);
      vc[2048 + h] = nw;
      ss = fmaf(nw, nw, ss);
    }
    sumsqReduce(ss, slack, ws + OFF_SUMSQ + pc * 96 + sidx(b, m, 0));
  }
}

// ============================ epilogue ============================

__global__ __launch_bounds__(256) void k_ln(float* ws, const float* __restrict__ g,
                                            const float* __restrict__ bb) {
  __shared__ float sm[8];
  float* p = ws + OFF_Z + (long)blockIdx.x * 1024;
  const int tid = threadIdx.x;
  float s = 0.f, s2 = 0.f;
  for (int j = tid; j < 1024; j += 256) {
    const float v = p[j];
    s += v;
    s2 = fmaf(v, v, s2);
  }
#pragma unroll
  for (int st = 32; st >= 1; st >>= 1) { s += __shfl_xor(s, st); s2 += __shfl_xor(s2, st); }
  if ((tid & 63) == 0) { sm[tid >> 6] = s; sm[4 + (tid >> 6)] = s2; }
  __syncthreads();
  const float S = sm[0] + sm[1] + sm[2] + sm[3];
  const float S2 = sm[4] + sm[5] + sm[6] + sm[7];
  const float mu = S * (1.f / 1024.f);
  const float var = S2 * (1.f / 1024.f) - mu * mu;
  const float inv = 1.f / sqrtf(var + 1e-5f);
  for (int j = tid; j < 1024; j += 256) {
    p[j] = fmaf((p[j] - mu) * inv, g[j], bb[j]);
  }
}

}  // namespace

extern "C" void kernel_launch(void* const* d_in, const int* in_sizes, int n_in,
                              void* d_out, int out_size, void* d_ws, size_t ws_size,
                              hipStream_t stream) {
  (void)in_sizes; (void)n_in; (void)out_size;
  if (ws_size < (size_t)WS_FLOATS * sizeof(float)) return;
  float* ws = (float*)d_ws;
  InPtrs ip;
  for (int i = 0; i < 31; i++) ip.p[i] = (const float*)d_in[i];

  k_probe<<<1, 64, 0, stream>>>(ws);
  k_p0<<<256, 256, 0, stream>>>(ws, ip);
  k_pc<<<5120, 256, 0, stream>>>(ws, ip);
  k_gbig2<<<1024, 512, 0, stream>>>((const float*)d_in[0], (const float*)d_in[25],
                                    (const float*)d_in[26], ws + OFF_Z, ws + OFF_FLAG);

  for (int t = 0; t < 128; t++) {
    k_s1<<<321, 512, 0, stream>>>(ws, t);
    k_s2<<<392, 256, 0, stream>>>(ws, t);
    k_s3<<<448, 512, 0, stream>>>(ws, t);
    k_s4<<<328, 512, 0, stream>>>(ws, t);
    k_s5<<<288, 512, 0, stream>>>(ws, t);
    k_s6<<<696, 256, 0, stream>>>(ws, t);
  }

  k_ln<<<8192, 256, 0, stream>>>(ws, (const float*)d_in[29], (const float*)d_in[30]);
  k_gbig2<<<1024, 512, 0, stream>>>(ws + OFF_Z, (const float*)d_in[27],
                                    (const float*)d_in[28], (float*)d_out, ws + OFF_FLAG);
}